// Round 7
// baseline (9655.066 us; speedup 1.0000x reference)
//
#include <hip/hip_runtime.h>
#include <cstdio>
#include <cmath>
#include <cstring>
#include <vector>

#ifndef M_PI
#define M_PI 3.14159265358979323846
#endif

// ---------------------------------------------------------------- constants
__host__ __device__ constexpr int off2c(int l) { return l * (2 * l - 1) * (2 * l + 1) / 3; }

static constexpr int S2_32 = off2c(32);   // 43680 = sum (2l+1)^2, l<32
static constexpr int S2_16 = off2c(16);   // 5456

// ---- host blob layout (bytes) ----
static constexpr size_t B_LAM   = 0;                       // 1024 double (eigenvalues, packed l*l+b)
static constexpr size_t B_BETAS = 1024 * 8;                // 227 double
static constexpr size_t B_U     = B_BETAS + 227 * 8;       // 43680 float (packed eigvec mats)
static constexpr size_t B_PAC   = B_U + (size_t)S2_32 * 4; // 6*63 float
static constexpr size_t B_PAS   = B_PAC + 378 * 4;
static constexpr size_t B_PGC   = B_PAS + 378 * 4;
static constexpr size_t B_PGS   = B_PGC + 378 * 4;
static constexpr size_t B_WB    = B_PGS + 378 * 4;         // 128
static constexpr size_t B_WH    = B_WB + 128 * 4;          // 64
static constexpr size_t B_WQ    = B_WH + 64 * 4;           // 32
static constexpr size_t B_WINT  = B_WQ + 32 * 4;           // 32
static constexpr size_t BLOB_BYTES = B_WINT + 32 * 4;      // 191800

__host__ __device__ constexpr size_t AL(size_t x) { return (x + 255) & ~(size_t)255; }

// ---- workspace layout ----
static constexpr size_t O_TRIG  = AL(BLOB_BYTES);                       // 227*1024 float2
static constexpr size_t O_WS2   = AL(O_TRIG + (size_t)227 * 1024 * 8);  // [128][1024] f
static constexpr size_t O_WIGH  = AL(O_WS2 + (size_t)128 * 1024 * 4);   // [64][S2_32] f
static constexpr size_t O_WIG16 = AL(O_WIGH + (size_t)64 * S2_32 * 4);  // [64][S2_16]
static constexpr size_t O_WIGQ  = AL(O_WIG16 + (size_t)64 * S2_16 * 4); // [32][S2_16]
static constexpr size_t O_D3    = AL(O_WIGQ + (size_t)32 * S2_16 * 4);  // [S2_32]
static constexpr size_t O_D4    = AL(O_D3 + (size_t)S2_32 * 4);         // [S2_16]
static constexpr size_t O_D5    = AL(O_D4 + (size_t)S2_16 * 4);
static constexpr size_t O_FEAT  = AL(O_D5 + (size_t)S2_16 * 4);         // 128 f
static constexpr size_t O_A0    = AL(O_FEAT + 512);
static constexpr size_t SZ_BIG  = 68ull << 20;
static constexpr size_t SZ_MED  = 24ull << 20;
static constexpr size_t O_A1    = O_A0 + SZ_BIG;
static constexpr size_t O_A2    = O_A1 + SZ_BIG;
static constexpr size_t O_A3    = O_A2 + SZ_MED;
static constexpr size_t O_A4    = O_A3 + SZ_MED;
static constexpr size_t WS_REQ  = O_A4 + SZ_MED;   // ~224 MiB

// ---------------------------------------------------------------- host tables
struct HostTables { std::vector<unsigned char> blob; };

static void jacobi_sym(int n, std::vector<double>& A, std::vector<double>& V, std::vector<double>& w) {
  V.assign((size_t)n * n, 0.0);
  for (int i = 0; i < n; i++) V[(size_t)i * n + i] = 1.0;
  for (int sweep = 0; sweep < 80; ++sweep) {
    double off = 0;
    for (int p = 0; p < n; p++)
      for (int q = p + 1; q < n; q++) off += A[(size_t)p * n + q] * A[(size_t)p * n + q];
    if (off < 1e-26) break;
    for (int p = 0; p < n - 1; p++) {
      for (int q = p + 1; q < n; q++) {
        double apq = A[(size_t)p * n + q];
        if (fabs(apq) < 1e-300) continue;
        double app = A[(size_t)p * n + p], aqq = A[(size_t)q * n + q];
        double theta = (aqq - app) / (2.0 * apq);
        double t = ((theta >= 0) ? 1.0 : -1.0) / (fabs(theta) + sqrt(theta * theta + 1.0));
        double c = 1.0 / sqrt(t * t + 1.0), s = t * c;
        for (int i = 0; i < n; i++) {
          double aip = A[(size_t)i * n + p], aiq = A[(size_t)i * n + q];
          A[(size_t)i * n + p] = c * aip - s * aiq;
          A[(size_t)i * n + q] = s * aip + c * aiq;
        }
        for (int i = 0; i < n; i++) {
          double api = A[(size_t)p * n + i], aqi = A[(size_t)q * n + i];
          A[(size_t)p * n + i] = c * api - s * aqi;
          A[(size_t)q * n + i] = s * api + c * aqi;
        }
        for (int i = 0; i < n; i++) {
          double vip = V[(size_t)i * n + p], viq = V[(size_t)i * n + q];
          V[(size_t)i * n + p] = c * vip - s * viq;
          V[(size_t)i * n + q] = s * vip + c * viq;
        }
      }
    }
  }
  for (int i = 0; i < n; i++) w[i] = A[(size_t)i * n + i];
}

static HostTables build_tables() {
  HostTables ht;
  ht.blob.assign(BLOB_BYTES, 0);
  double* lam  = (double*)(ht.blob.data() + B_LAM);
  double* bet  = (double*)(ht.blob.data() + B_BETAS);
  float*  U    = (float*)(ht.blob.data() + B_U);
  float*  PAc  = (float*)(ht.blob.data() + B_PAC);
  float*  PAs  = (float*)(ht.blob.data() + B_PAS);
  float*  PGc  = (float*)(ht.blob.data() + B_PGC);
  float*  PGs  = (float*)(ht.blob.data() + B_PGS);
  float*  wbf  = (float*)(ht.blob.data() + B_WB);
  float*  whf  = (float*)(ht.blob.data() + B_WH);
  float*  wqf  = (float*)(ht.blob.data() + B_WQ);
  float*  wint = (float*)(ht.blob.data() + B_WINT);

  auto dh = [](int b, std::vector<double>& beta, std::vector<double>& w) {
    beta.resize(2 * b); w.resize(2 * b);
    for (int k = 0; k < 2 * b; k++) {
      double bk = M_PI * (2 * k + 1) / (4.0 * b);
      beta[k] = bk;
      double s = 0;
      for (int j = 0; j < b; j++) s += sin((2 * j + 1) * bk) / (2 * j + 1);
      w[k] = (2.0 / b) * sin(bk) * s;
    }
  };
  std::vector<double> bb, wb64, bh, wh32, bq, wq16;
  dh(64, bb, wb64); dh(32, bh, wh32); dh(16, bq, wq16);
  for (int k = 0; k < 128; k++) { bet[k] = bb[k]; wbf[k] = (float)wb64[k]; }
  for (int k = 0; k < 64; k++)  { bet[128 + k] = bh[k]; whf[k] = (float)wh32[k]; }
  for (int k = 0; k < 32; k++)  { bet[192 + k] = bq[k]; wqf[k] = (float)wq16[k]; }
  bet[224] = M_PI / 16.0; bet[225] = M_PI / 8.0; bet[226] = M_PI / 4.0;
  double sq = 0; for (int k = 0; k < 32; k++) sq += wq16[k];
  for (int k = 0; k < 32; k++) wint[k] = (float)(wq16[k] / (sq * 1024.0));

  // eigensystems: B real symm tridiag, zero diag, offdiag -c_j/2 (see D=diag(i^j) transform of exp(beta K))
  std::vector<double> A, V, w;
  for (int l = 0; l < 32; l++) {
    int n = 2 * l + 1;
    A.assign((size_t)n * n, 0.0);
    for (int j = 0; j < n - 1; j++) {
      double mj = -l + j;
      double c = sqrt((double)l * (l + 1) - mj * (mj + 1));
      A[(size_t)j * n + j + 1] = -c / 2.0;
      A[(size_t)(j + 1) * n + j] = -c / 2.0;
    }
    w.assign(n, 0.0);
    jacobi_sym(n, A, V, w);
    for (int r = 0; r < n; r++)
      for (int b2 = 0; b2 < n; b2++) U[off2c(l) + r * n + b2] = (float)V[(size_t)r * n + b2];
    for (int b2 = 0; b2 < n; b2++) lam[l * l + b2] = (double)llround(w[b2]); // Jy spectrum is exactly -l..l
  }
  for (int a = 0; a < 6; a++) {
    double al = 2.0 * M_PI * a / 6.0;
    for (int mi = 0; mi < 63; mi++) { int m = mi - 31; PAc[a * 63 + mi] = (float)cos(m * al); PAs[a * 63 + mi] = (float)sin(m * al); }
  }
  for (int c = 0; c < 6; c++) {
    double ga = -2.0 * M_PI + 4.0 * M_PI * c / 5.0;  // linspace(-2pi, 2pi, 6)
    for (int mi = 0; mi < 63; mi++) { int m = mi - 31; PGc[c * 63 + mi] = (float)cos(m * ga); PGs[c * 63 + mi] = (float)sin(m * ga); }
  }
  return ht;
}

// ---------------------------------------------------------------- device helpers
#define DEVFN static __device__ __forceinline__
DEVFN int isqrt_i(int p) {
  int l = (int)sqrtf((float)p);
  while (l * l > p) --l;
  while ((l + 1) * (l + 1) <= p) ++l;
  return l;
}
DEVFN void cmul_acc(float2& acc, float2 a, float2 w) {
  acc.x += a.x * w.x - a.y * w.y;
  acc.y += a.x * w.y + a.y * w.x;
}
DEVFN void crot(float2& w, float2 st) {
  float nx = w.x * st.x - w.y * st.y;
  w.y = w.x * st.y + w.y * st.x;
  w.x = nx;
}

// ---------------------------------------------------------------- kernels
// trig tables: cos/sin(beta * lambda) for every (beta row, packed l*l+b)
__global__ void k_trig(const double* __restrict__ lam, const double* __restrict__ betas, float2* __restrict__ trig) {
  int id = blockIdx.x * blockDim.x + threadIdx.x;
  if (id >= 227 * 1024) return;
  int row = id >> 10, p = id & 1023;
  double a = betas[row] * lam[p];
  double s, c;
  sincos(a, &s, &c);
  trig[id] = make_float2((float)c, (float)s);
}

// W_s2[k][l*l+mi] = d^l_{m0}(beta_b[k]) * wb[k]
__global__ void k_ws2(const float* __restrict__ U, const float2* __restrict__ Tb, const float* __restrict__ wb, float* __restrict__ W) {
  int id = blockIdx.x * blockDim.x + threadIdx.x;
  if (id >= 128 * 1024) return;
  int k = id >> 10, p = id & 1023;
  int l = isqrt_i(p); int mi = p - l * l; int n = 2 * l + 1;
  const float* Ul = U + off2c(l);
  const float2* T = Tb + (size_t)k * 1024 + l * l;
  float ac = 0, as = 0;
  for (int b = 0; b < n; b++) { float uu = Ul[mi * n + b] * Ul[l * n + b]; ac += uu * T[b].x; as += uu * T[b].y; }
  int q = (mi - l) & 3;
  float v = (q & 1) ? as : ac; if (q & 2) v = -v;
  W[id] = v * wb[k];
}

// generic packed wigner-d build: out[k][off2(l)+r*(2l+1)+c] = d^l_{rc}(beta_k)
__global__ void k_wig(const float* __restrict__ U, const float2* __restrict__ trig, float* __restrict__ out, int S2L) {
  int l = blockIdx.y, k = blockIdx.z;
  int n = 2 * l + 1;
  int t = blockIdx.x * blockDim.x + threadIdx.x;
  if (t >= n * n) return;
  int r = t / n, c = t - r * n;
  const float* Ul = U + off2c(l);
  const float2* T = trig + (size_t)k * 1024 + l * l;
  float ac = 0, as = 0;
  for (int b = 0; b < n; b++) { float uu = Ul[r * n + b] * Ul[c * n + b]; ac += uu * T[b].x; as += uu * T[b].y; }
  int q = (r - c) & 3;
  float v = (q & 1) ? as : ac; if (q & 2) v = -v;
  out[(size_t)k * S2L + off2c(l) + t] = v;
}

// 1x1 conv + relu: h1[z,o,hw]
__global__ void k_conv1(const float* __restrict__ x, const float* __restrict__ w1, const float* __restrict__ b1, float* __restrict__ h1) {
  int id = blockIdx.x * blockDim.x + threadIdx.x;
  if (id >= 2 * 16 * 16384) return;
  int hw = id & 16383; int zo = id >> 14; int o = zo & 15; int z = zo >> 4;
  float acc = b1[o];
  for (int c = 0; c < 4; c++) acc += w1[o * 4 + c] * x[(size_t)(z * 4 + c) * 16384 + hw];
  h1[id] = fmaxf(acc, 0.f);
}

// alpha-DFT (layer2): per block 4 rows staged in LDS; 63 outputs/row via recurrence twiddles
__global__ void k_dft_a(const float* __restrict__ h1, float2* __restrict__ xf) {
  __shared__ float rows[4][128];
  int tid = threadIdx.x;
  int r0 = blockIdx.x * 4;
  for (int idx = tid; idx < 4 * 128; idx += 256) rows[idx >> 7][idx & 127] = h1[(size_t)r0 * 128 + idx];
  __syncthreads();
  int r = tid >> 6;         // 0..3
  int j = tid & 63;         // 0..63; j<63 active
  if (j >= 63) return;
  float ang = -6.28318530717958647692f * (float)(j - 31) / 128.f;
  float2 st; __sincosf(ang, &st.y, &st.x);
  float2 w = make_float2(1.f, 0.f);
  float2 acc = make_float2(0.f, 0.f);
  const float* row = rows[r];
  for (int a = 0; a < 128; a++) {
    float hv = row[a];
    acc.x += hv * w.x; acc.y += hv * w.y;
    crot(w, st);
  }
  xf[(size_t)(r0 + r) * 63 + j] = make_float2(acc.x / 128.f, acc.y / 128.f);
}

// X2[zi][l*l+mi] = sum_k Ws2[k][p] * xf2[zi,k,jm]
__global__ void k_x2(const float* __restrict__ W, const float2* __restrict__ xf, float2* __restrict__ X) {
  int id = blockIdx.x * blockDim.x + threadIdx.x;
  if (id >= 2 * 16 * 1024) return;
  int p = id & 1023; int zi = id >> 10;
  int l = isqrt_i(p); int mi = p - l * l; int jm = mi - l + 31;
  float2 acc = make_float2(0.f, 0.f);
  for (int k = 0; k < 128; k++) {
    float w = W[(size_t)k * 1024 + p];
    float2 v = xf[((size_t)zi * 128 + k) * 63 + jm];
    acc.x += w * v.x; acc.y += w * v.y;
  }
  X[id] = acc;
}

// kappa2[i*16+o][j] = sum_a k2[i,o,a] e^{i (j-31) alpha_a}
__global__ void k_kap2(const float* __restrict__ k2, const float* __restrict__ PAc, const float* __restrict__ PAs, float2* __restrict__ kap) {
  int id = blockIdx.x * blockDim.x + threadIdx.x;
  if (id >= 16 * 16 * 63) return;
  int j = id % 63; int io = id / 63;
  float2 acc = make_float2(0.f, 0.f);
  for (int a = 0; a < 6; a++) {
    float kv = k2[io * 6 + a];
    acc.x += kv * PAc[a * 63 + j]; acc.y += kv * PAs[a * 63 + j];
  }
  kap[id] = acc;
}

// Y2[z,o,pk] = sum_i X2[z,i,l*l+mi] * conj(d^l_{n0} kappa2[i,o,jn])
__global__ void k_y2(const float2* __restrict__ X, const float2* __restrict__ kap, const float* __restrict__ d3, float2* __restrict__ Y) {
  int l = blockIdx.y; int n21 = 2 * l + 1;
  int t = blockIdx.x * blockDim.x + threadIdx.x;
  if (t >= n21 * n21) return;
  int zo = blockIdx.z; int o = zo & 15; int z = zo >> 4;
  int mi = t / n21, ni = t - mi * n21;
  float dv = d3[off2c(l) + ni * n21 + l];
  int jn = ni - l + 31;
  float2 acc = make_float2(0.f, 0.f);
  for (int i = 0; i < 16; i++) {
    float2 xv = X[(size_t)(z * 16 + i) * 1024 + l * l + mi];
    float2 kv = kap[(size_t)(i * 16 + o) * 63 + jn];
    acc.x += dv * (xv.x * kv.x + xv.y * kv.y);
    acc.y += dv * (xv.y * kv.x - xv.x * kv.y);
  }
  Y[(size_t)(z * 16 + o) * S2_32 + off2c(l) + t] = acc;
}

// ---------------------------------------------------------------- k_y as fused complex GEMM (v2)
// Y[z,o,l,mi,ni] = sum_{i,p} X[z,i,l,mi,p] * (d^l[ni,p] * conj(kap[i,o,jn,jp]))
// One M-tile covers all of M=n21 (BM>=n21). 4-col micro-tile with float4 LDS reads.
template <int CI, int CO, int L, int BM>
__global__ __launch_bounds__(256) void k_y_gemm(const float2* __restrict__ X, const float2* __restrict__ kap,
                                                const float* __restrict__ dtab, float2* __restrict__ Y, int S2L) {
  constexpr int NF = 2 * L - 1;
  constexpr int BN = 64, BK = 32;
  constexpr int IM = BM / 16;     // rows per thread (4 for BM=64, 2 for BM=32)
  const int l = blockIdx.y;
  const int n21 = 2 * l + 1;
  const int Kdim = CI * n21;
  const int N = CO * n21;
  const int ntn = (N + BN - 1) / BN;
  if ((int)blockIdx.x >= ntn) return;
  const int tn = blockIdx.x;
  const int z = blockIdx.z;
  const int off = off2c(l);
  const float2* Xz = X + (size_t)z * CI * S2L + off;
  float2* Yz = Y + (size_t)z * CO * S2L + off;
  const float* dl = dtab + off;

  __shared__ float2 As[BK][BM + 2];
  __shared__ float2 Bs[BK][BN + 2];
  __shared__ int nLUT_o[BN];
  __shared__ short nLUT_ni[BN];

  const int tid = threadIdx.x;
  if (tid < BN) {
    int ng = tn * BN + tid;
    int o = ng / n21;
    nLUT_o[tid] = (ng < N) ? o : -1;
    nLUT_ni[tid] = (short)(ng - o * n21);
  }
  const int kk = tid & 31;       // K-lane for staging
  const int rr = tid >> 5;       // 0..7
  const int r0 = IM * (tid >> 4);      // row base (step IM)
  const int c0 = 4 * (tid & 15);       // col base
  float2 acc[IM][4];
  #pragma unroll
  for (int a = 0; a < IM; a++)
    #pragma unroll
    for (int b = 0; b < 4; b++) acc[a][b] = make_float2(0.f, 0.f);
  __syncthreads();

  for (int k0 = 0; k0 < Kdim; k0 += BK) {
    int kg = k0 + kk;
    bool kok = kg < Kdim;
    int kgc = kok ? kg : (Kdim - 1);
    int i = (unsigned)kgc / (unsigned)n21;
    int p = kgc - i * n21;
    // A fill: As[kk][m] = X[z,i,m,p]
    #pragma unroll
    for (int s = 0; s < BM / 8; s++) {
      int m = rr + s * 8;
      float2 v = make_float2(0.f, 0.f);
      if (kok && m < n21) v = Xz[(size_t)i * S2L + m * n21 + p];
      As[kk][m] = v;
    }
    // B fill: Bs[kk][nn] = d[ni,p] * conj(kap[i,o,jn,jp])
    int jp = p - l + (L - 1);
    #pragma unroll
    for (int s = 0; s < 8; s++) {
      int nn = rr + s * 8;
      float2 v = make_float2(0.f, 0.f);
      int o = nLUT_o[nn];
      if (kok && o >= 0) {
        int ni = nLUT_ni[nn];
        float dv = dl[ni * n21 + p];
        int jn = ni - l + (L - 1);
        float2 kv = kap[(size_t)(i * CO + o) * NF * NF + jn * NF + jp];
        v = make_float2(dv * kv.x, -dv * kv.y);
      }
      Bs[kk][nn] = v;
    }
    __syncthreads();
    #pragma unroll
    for (int q = 0; q < BK; q++) {
      float2 av[IM];
      #pragma unroll
      for (int t = 0; t < IM; t += 2) {
        float4 a = *(const float4*)&As[q][r0 + t];
        av[t] = make_float2(a.x, a.y);
        av[t + 1] = make_float2(a.z, a.w);
      }
      float4 b0 = *(const float4*)&Bs[q][c0];
      float4 b1 = *(const float4*)&Bs[q][c0 + 2];
      float2 bv[4] = {make_float2(b0.x, b0.y), make_float2(b0.z, b0.w),
                      make_float2(b1.x, b1.y), make_float2(b1.z, b1.w)};
      #pragma unroll
      for (int im = 0; im < IM; im++)
        #pragma unroll
        for (int jn = 0; jn < 4; jn++) {
          acc[im][jn].x += av[im].x * bv[jn].x - av[im].y * bv[jn].y;
          acc[im][jn].y += av[im].x * bv[jn].y + av[im].y * bv[jn].x;
        }
    }
    __syncthreads();
  }
  #pragma unroll
  for (int im = 0; im < IM; im++) {
    int mg = r0 + im;
    if (mg >= n21) continue;
    #pragma unroll
    for (int jn = 0; jn < 4; jn++) {
      int nn = c0 + jn;
      int o = nLUT_o[nn];
      if (o < 0) continue;
      Yz[(size_t)o * S2L + mg * n21 + nLUT_ni[nn]] = acc[im][jn];
    }
  }
}

// F[zc,k,jm,jn] = sum_l (2l+1) * wig[k][pk] * Y[zc][pk]  (dense in (jm,jn))
__global__ void k_f(const float* __restrict__ wig, const float2* __restrict__ Y, float2* __restrict__ F,
                    int nzc, int NK, int L, int S2L) {
  int NF = 2 * L - 1;
  size_t id = (size_t)blockIdx.x * blockDim.x + threadIdx.x;
  size_t tot = (size_t)nzc * NK * NF * NF;
  if (id >= tot) return;
  int jn = (int)(id % NF); size_t r1 = id / NF;
  int jm = (int)(r1 % NF); size_t r2 = r1 / NF;
  int k = (int)(r2 % NK); int zc = (int)(r2 / NK);
  int m = jm - (L - 1), n = jn - (L - 1);
  int am = m < 0 ? -m : m, an = n < 0 ? -n : n;
  int lmin = am > an ? am : an;
  float2 acc = make_float2(0.f, 0.f);
  const float* wk = wig + (size_t)k * S2L;
  const float2* Yc = Y + (size_t)zc * S2L;
  for (int l = lmin; l < L; l++) {
    int n21 = 2 * l + 1;
    int pk = off2c(l) + (m + l) * n21 + (n + l);
    float w = wk[pk] * (float)n21;
    float2 yv = Yc[pk];
    acc.x += w * yv.x; acc.y += w * yv.y;
  }
  F[id] = acc;
}

// fused 2-stage inverse DFT  F[zc,k,:,:] -> h[zc,k,u,v] (+bias, relu)
// F staged in LDS (broadcast reads), recurrence twiddles, Gt in LDS (2-way free).
template <int L, int B2>
__global__ void k_synth(const float2* __restrict__ F, const float* __restrict__ bias, float* __restrict__ h, int C, int NK) {
  constexpr int NF = 2 * L - 1;
  constexpr float TWO_PI = 6.28318530717958647692f;
  __shared__ float2 Ft[NF * NF];
  __shared__ float2 Gt[NF * B2];
  int bid = blockIdx.x;         // zc*NK + k
  int zc = bid / NK;
  int c = zc % C;
  int tid = threadIdx.x, nt = blockDim.x;
  const float2* Fb = F + (size_t)bid * NF * NF;
  for (int idx = tid; idx < NF * NF; idx += nt) Ft[idx] = Fb[idx];
  __syncthreads();
  // stage 1: Gt[jm][v] = sum_jn Ft[jm][jn] * e^{+i 2pi v (jn-(L-1))/B2}
  {
    int v = tid & (B2 - 1);    // invariant across idx iterations (nt % B2 == 0)
    float a0 = TWO_PI * (float)(((-(L - 1) * v) % B2 + B2) % B2) / (float)B2;
    float as = TWO_PI * (float)v / (float)B2;
    float2 w0, st;
    __sincosf(a0, &w0.y, &w0.x);
    __sincosf(as, &st.y, &st.x);
    for (int idx = tid; idx < NF * B2; idx += nt) {
      int jm = idx / B2;
      const float2* Fr = Ft + jm * NF;
      float2 acc = make_float2(0.f, 0.f);
      float2 w = w0;
      for (int jn = 0; jn < NF; jn++) {
        cmul_acc(acc, Fr[jn], w);   // LDS broadcast (uniform per sub-wave)
        crot(w, st);
      }
      Gt[idx] = acc;
    }
  }
  __syncthreads();
  float bv = bias[c];
  float* hb = h + (size_t)bid * B2 * B2;
  for (int idx = tid; idx < B2 * B2; idx += nt) {
    int u = idx / B2, v = idx & (B2 - 1);
    float a0 = TWO_PI * (float)(((-(L - 1) * u) % B2 + B2) % B2) / (float)B2;
    float as = TWO_PI * (float)u / (float)B2;
    float2 w, st;
    __sincosf(a0, &w.y, &w.x);
    __sincosf(as, &st.y, &st.x);
    float acc = 0;
    for (int jm = 0; jm < NF; jm++) {
      float2 gv = Gt[jm * B2 + v];
      acc += gv.x * w.x - gv.y * w.y;
      crot(w, st);
    }
    hb[idx] = fmaxf(acc + bv, 0.f);
  }
}

// fused 2-stage forward DFT: h[zc,k,:,:] -> xf[zc,k,jm,jn] (truncated, /B2^2)
// h staged in LDS; Tt split re/im (stride-1 lane reads, conflict-free).
template <int L, int B2>
__global__ void k_fwd(const float* __restrict__ h, float2* __restrict__ xf) {
  constexpr int NF = 2 * L - 1;
  constexpr float TWO_PI = 6.28318530717958647692f;
  __shared__ float ht[B2 * B2];
  __shared__ float Ttr[B2 * NF];
  __shared__ float Tti[B2 * NF];
  int bid = blockIdx.x;
  int tid = threadIdx.x, nt = blockDim.x;
  const float* hb = h + (size_t)bid * B2 * B2;
  for (int idx = tid; idx < B2 * B2; idx += nt) ht[idx] = hb[idx];
  __syncthreads();
  for (int idx = tid; idx < B2 * NF; idx += nt) {
    int u = idx / NF, jn = idx - u * NF;
    float as = -TWO_PI * (float)(jn - (L - 1)) / (float)B2;
    float2 st, w = make_float2(1.f, 0.f);
    __sincosf(as, &st.y, &st.x);
    float2 acc = make_float2(0.f, 0.f);
    const float* hr = ht + u * B2;
    for (int v = 0; v < B2; v++) {
      float hv = hr[v];               // LDS broadcast
      acc.x += hv * w.x; acc.y += hv * w.y;
      crot(w, st);
    }
    Ttr[idx] = acc.x; Tti[idx] = acc.y;
  }
  __syncthreads();
  float2* xb = xf + (size_t)bid * NF * NF;
  const float inv = 1.f / ((float)B2 * (float)B2);
  for (int idx = tid; idx < NF * NF; idx += nt) {
    int jm = idx / NF, jn = idx - jm * NF;
    float as = -TWO_PI * (float)(jm - (L - 1)) / (float)B2;
    float2 st, w = make_float2(1.f, 0.f);
    __sincosf(as, &st.y, &st.x);
    float2 acc = make_float2(0.f, 0.f);
    for (int u = 0; u < B2; u++) {
      float2 tv = make_float2(Ttr[u * NF + jn], Tti[u * NF + jn]);
      cmul_acc(acc, tv, w);
      crot(w, st);
    }
    xb[idx] = make_float2(acc.x * inv, acc.y * inv);
  }
}

// X[zi][pk] = sum_k wgt[k] * wig[k][pk] * xf[zi,k,jm,jn]
__global__ void k_xc(const float* __restrict__ wig, const float* __restrict__ wgt, const float2* __restrict__ xf,
                     float2* __restrict__ X, int NK, int L, int S2L) {
  int NF = 2 * L - 1;
  int l = blockIdx.y; int n21 = 2 * l + 1;
  int t = blockIdx.x * blockDim.x + threadIdx.x;
  if (t >= n21 * n21) return;
  int zi = blockIdx.z;
  int mi = t / n21, ni = t - mi * n21;
  int jm = mi - l + (L - 1), jn = ni - l + (L - 1);
  int pk = off2c(l) + t;
  float2 acc = make_float2(0.f, 0.f);
  for (int k = 0; k < NK; k++) {
    float w = wig[(size_t)k * S2L + pk] * wgt[k];
    float2 v = xf[((size_t)zi * NK + k) * NF * NF + jm * NF + jn];
    acc.x += w * v.x; acc.y += w * v.y;
  }
  X[(size_t)zi * S2L + pk] = acc;
}

// kappa[io][jn][jp] = sum_{a,c} ker[io,a*6+c] e^{i m_n alpha_a} e^{i m_p gamma_c}
__global__ void k_kap(const float* __restrict__ ker, const float* __restrict__ PAc, const float* __restrict__ PAs,
                      const float* __restrict__ PGc, const float* __restrict__ PGs,
                      float2* __restrict__ kap, int NIO, int NF, int poff) {
  int id = blockIdx.x * blockDim.x + threadIdx.x;
  if (id >= NIO * NF * NF) return;
  int jp = id % NF; int r = id / NF; int jn = r % NF; int io = r / NF;
  float2 acc = make_float2(0.f, 0.f);
  for (int a = 0; a < 6; a++) {
    float pac = PAc[a * 63 + jn + poff], pas = PAs[a * 63 + jn + poff];
    for (int c = 0; c < 6; c++) {
      float kv = ker[io * 36 + a * 6 + c];
      float pgc = PGc[c * 63 + jp + poff], pgs = PGs[c * 63 + jp + poff];
      acc.x += kv * (pac * pgc - pas * pgs);
      acc.y += kv * (pac * pgs + pas * pgc);
    }
  }
  kap[id] = acc;
}

// feat[zc] = sum_{beta,u,v} h5[zc,beta,u,v] * wint[beta]
__global__ void k_feat(const float* __restrict__ h5, const float* __restrict__ wint, float* __restrict__ feat) {
  __shared__ float red[256];
  int zc = blockIdx.x;
  const float* hb = h5 + (size_t)zc * 32768;
  float acc = 0;
  for (int idx = threadIdx.x; idx < 32768; idx += 256) acc += hb[idx] * wint[idx >> 10];
  red[threadIdx.x] = acc;
  __syncthreads();
  for (int s = 128; s > 0; s >>= 1) { if (threadIdx.x < s) red[threadIdx.x] += red[threadIdx.x + s]; __syncthreads(); }
  if (threadIdx.x == 0) feat[zc] = red[0];
}

// MLP head per batch row
__global__ void k_head(const float* __restrict__ feat, const float* __restrict__ m, const float* __restrict__ wm,
                       const float* __restrict__ bm, const float* __restrict__ wl1, const float* __restrict__ bl1,
                       const float* __restrict__ wl2, const float* __restrict__ bl2, float* __restrict__ out) {
  __shared__ float zin[68];
  __shared__ float red[512];
  int z = blockIdx.x, tid = threadIdx.x;
  if (tid < 64) zin[tid] = feat[z * 64 + tid];
  else if (tid < 68) zin[tid] = fmaxf(m[z] * wm[tid - 64] + bm[tid - 64], 0.f);
  __syncthreads();
  float part = 0;
  for (int q = tid; q < 500; q += 512) {
    float acc = bl1[q];
    for (int j = 0; j < 68; j++) acc += zin[j] * wl1[q * 68 + j];
    part += fmaxf(acc, 0.f) * wl2[q];
  }
  red[tid] = part;
  __syncthreads();
  for (int s = 256; s > 0; s >>= 1) { if (tid < s) red[tid] += red[tid + s]; __syncthreads(); }
  if (tid == 0) out[z] = red[0] + bl2[0];
}

// ---------------------------------------------------------------- launch
extern "C" void kernel_launch(void* const* d_in, const int* in_sizes, int n_in,
                              void* d_out, int out_size, void* d_ws, size_t ws_size,
                              hipStream_t stream) {
  static HostTables HT = build_tables();  // host-only, once

  if (ws_size < WS_REQ) {
    fprintf(stderr, "[s2cnn] ws too small: need %zu bytes, got %zu\n", (size_t)WS_REQ, ws_size);
    return;
  }
  if (n_in < 18) { fprintf(stderr, "[s2cnn] bad n_in %d\n", n_in); return; }

  const float* x   = (const float*)d_in[0];
  const float* mI  = (const float*)d_in[1];
  const float* w1  = (const float*)d_in[2];
  const float* b1  = (const float*)d_in[3];
  const float* k2  = (const float*)d_in[4];
  const float* bb2 = (const float*)d_in[5];
  const float* k3  = (const float*)d_in[6];
  const float* bb3 = (const float*)d_in[7];
  const float* k4  = (const float*)d_in[8];
  const float* bb4 = (const float*)d_in[9];
  const float* k5  = (const float*)d_in[10];
  const float* bb5 = (const float*)d_in[11];
  const float* wm  = (const float*)d_in[12];
  const float* bm  = (const float*)d_in[13];
  const float* wl1 = (const float*)d_in[14];
  const float* bl1 = (const float*)d_in[15];
  const float* wl2 = (const float*)d_in[16];
  const float* bl2 = (const float*)d_in[17];
  float* out = (float*)d_out;

  char* ws = (char*)d_ws;
  // upload constant blob (192 KB)
  hipMemcpyAsync(ws, HT.blob.data(), BLOB_BYTES, hipMemcpyHostToDevice, stream);

  const double* dLam  = (const double*)(ws + B_LAM);
  const double* dBet  = (const double*)(ws + B_BETAS);
  const float*  dU    = (const float*)(ws + B_U);
  const float*  dPAc  = (const float*)(ws + B_PAC);
  const float*  dPAs  = (const float*)(ws + B_PAS);
  const float*  dPGc  = (const float*)(ws + B_PGC);
  const float*  dPGs  = (const float*)(ws + B_PGS);
  const float*  dWb   = (const float*)(ws + B_WB);
  const float*  dWh   = (const float*)(ws + B_WH);
  const float*  dWq   = (const float*)(ws + B_WQ);
  const float*  dWint = (const float*)(ws + B_WINT);

  float2* TRIG = (float2*)(ws + O_TRIG);
  float2* Tb = TRIG;                 // 128 rows
  float2* Th = TRIG + (size_t)128 * 1024;
  float2* Tq = TRIG + (size_t)192 * 1024;
  float2* Ts16 = TRIG + (size_t)224 * 1024;
  float2* Ts8  = TRIG + (size_t)225 * 1024;
  float2* Ts4  = TRIG + (size_t)226 * 1024;
  float* WS2   = (float*)(ws + O_WS2);
  float* WIGH  = (float*)(ws + O_WIGH);
  float* WIG16 = (float*)(ws + O_WIG16);
  float* WIGQ  = (float*)(ws + O_WIGQ);
  float* D3    = (float*)(ws + O_D3);
  float* D4    = (float*)(ws + O_D4);
  float* D5    = (float*)(ws + O_D5);
  float* FEAT  = (float*)(ws + O_FEAT);
  char* A0 = ws + O_A0;
  char* A1 = ws + O_A1;
  char* A2 = ws + O_A2;
  char* A3 = ws + O_A3;
  char* A4 = ws + O_A4;

  // ---- build tables on device (cheap, every call: ws is re-poisoned)
  k_trig<<<(227 * 1024 + 255) / 256, 256, 0, stream>>>(dLam, dBet, TRIG);
  k_ws2<<<(128 * 1024 + 255) / 256, 256, 0, stream>>>(dU, Tb, dWb, WS2);
  k_wig<<<dim3(16, 32, 64), 256, 0, stream>>>(dU, Th, WIGH, S2_32);
  k_wig<<<dim3(4, 16, 64), 256, 0, stream>>>(dU, Th, WIG16, S2_16);
  k_wig<<<dim3(4, 16, 32), 256, 0, stream>>>(dU, Tq, WIGQ, S2_16);
  k_wig<<<dim3(16, 32, 1), 256, 0, stream>>>(dU, Ts16, D3, S2_32);
  k_wig<<<dim3(4, 16, 1), 256, 0, stream>>>(dU, Ts8, D4, S2_16);
  k_wig<<<dim3(4, 16, 1), 256, 0, stream>>>(dU, Ts4, D5, S2_16);

  // ---- layer 1: 1x1 conv + relu -> h1 (A2)
  float* h1 = (float*)A2;
  k_conv1<<<(2 * 16 * 16384 + 255) / 256, 256, 0, stream>>>(x, w1, b1, h1);

  // ---- layer 2: s2 conv
  float2* xf2 = (float2*)A0;
  k_dft_a<<<2 * 16 * 128 / 4, 256, 0, stream>>>(h1, xf2);
  float2* X2 = (float2*)A3;
  k_x2<<<(2 * 16 * 1024 + 255) / 256, 256, 0, stream>>>(WS2, xf2, X2);
  float2* kap2 = (float2*)A4;
  k_kap2<<<(16 * 16 * 63 + 255) / 256, 256, 0, stream>>>(k2, dPAc, dPAs, kap2);
  float2* Y2 = (float2*)A1;
  k_y2<<<dim3(16, 32, 32), 256, 0, stream>>>(X2, kap2, D3, Y2);
  float2* F2 = (float2*)A0;
  k_f<<<(2 * 16 * 64 * 63 * 63 + 255) / 256, 256, 0, stream>>>(WIGH, Y2, F2, 32, 64, 32, S2_32);
  float* h2 = (float*)A1;
  k_synth<32, 64><<<2 * 16 * 64, 256, 0, stream>>>(F2, bb2, h2, 16, 64);

  // ---- layer 3: so3 conv (b=32, L=32)
  float2* xf3 = (float2*)A0;
  k_fwd<32, 64><<<2 * 16 * 64, 256, 0, stream>>>(h2, xf3);
  float2* X3 = (float2*)A2;
  k_xc<<<dim3(16, 32, 2 * 16), 256, 0, stream>>>(WIGH, dWh, xf3, X3, 64, 32, S2_32);
  float2* kap3 = (float2*)A3;
  k_kap<<<(16 * 32 * 63 * 63 + 255) / 256, 256, 0, stream>>>(k3, dPAc, dPAs, dPGc, dPGs, kap3, 16 * 32, 63, 0);
  float2* Y3 = (float2*)A4;
  k_y_gemm<16, 32, 32, 64><<<dim3(32, 32, 2), 256, 0, stream>>>(X3, kap3, D3, Y3, S2_32);
  float* h3 = (float*)A1;
  for (int z = 0; z < 2; z++) {
    float2* F3 = (float2*)A0;
    k_f<<<(32 * 64 * 63 * 63 + 255) / 256, 256, 0, stream>>>(WIGH, Y3 + (size_t)z * 32 * S2_32, F3, 32, 64, 32, S2_32);
    k_synth<32, 64><<<32 * 64, 256, 0, stream>>>(F3, bb3, h3 + (size_t)z * 32 * 64 * 4096, 32, 64);
  }

  // ---- layer 4: so3 conv (b=32 -> 16, L=16)
  float2* xf4 = (float2*)A0;
  k_fwd<16, 64><<<2 * 32 * 64, 256, 0, stream>>>(h3, xf4);
  float2* X4 = (float2*)A2;
  k_xc<<<dim3(4, 16, 2 * 32), 256, 0, stream>>>(WIG16, dWh, xf4, X4, 64, 16, S2_16);
  float2* kap4 = (float2*)A3;
  k_kap<<<(32 * 32 * 31 * 31 + 255) / 256, 256, 0, stream>>>(k4, dPAc, dPAs, dPGc, dPGs, kap4, 32 * 32, 31, 16);
  float2* Y4 = (float2*)A4;
  k_y_gemm<32, 32, 16, 32><<<dim3(16, 16, 2), 256, 0, stream>>>(X4, kap4, D4, Y4, S2_16);
  float2* F4 = (float2*)A1;
  k_f<<<(2 * 32 * 32 * 31 * 31 + 255) / 256, 256, 0, stream>>>(WIGQ, Y4, F4, 64, 32, 16, S2_16);
  float* h4 = (float*)A0;
  k_synth<16, 32><<<2 * 32 * 32, 256, 0, stream>>>(F4, bb4, h4, 32, 32);

  // ---- layer 5: so3 conv (b=16, L=16)
  float2* xf5 = (float2*)A1;
  k_fwd<16, 32><<<2 * 32 * 32, 256, 0, stream>>>(h4, xf5);
  float2* X5 = (float2*)A2;
  k_xc<<<dim3(4, 16, 2 * 32), 256, 0, stream>>>(WIGQ, dWq, xf5, X5, 32, 16, S2_16);
  float2* kap5 = (float2*)A3;
  k_kap<<<(32 * 64 * 31 * 31 + 255) / 256, 256, 0, stream>>>(k5, dPAc, dPAs, dPGc, dPGs, kap5, 32 * 64, 31, 16);
  float2* Y5 = (float2*)A4;
  k_y_gemm<32, 64, 16, 32><<<dim3(31, 16, 2), 256, 0, stream>>>(X5, kap5, D5, Y5, S2_16);
  float2* F5 = (float2*)A0;
  k_f<<<(2 * 64 * 32 * 31 * 31 + 255) / 256, 256, 0, stream>>>(WIGQ, Y5, F5, 128, 32, 16, S2_16);
  float* h5 = (float*)A1;
  k_synth<16, 32><<<2 * 64 * 32, 256, 0, stream>>>(F5, bb5, h5, 64, 32);

  // ---- head
  k_feat<<<128, 256, 0, stream>>>(h5, dWint, FEAT);
  k_head<<<2, 512, 0, stream>>>(FEAT, mI, wm, bm, wl1, bl1, wl2, bl2, out);
}

// Round 8
// 9128.553 us; speedup vs baseline: 1.0577x; 1.0577x over previous
//
#include <hip/hip_runtime.h>
#include <cstdio>
#include <cmath>
#include <cstring>
#include <vector>

#ifndef M_PI
#define M_PI 3.14159265358979323846
#endif

// ---------------------------------------------------------------- constants
__host__ __device__ constexpr int off2c(int l) { return l * (2 * l - 1) * (2 * l + 1) / 3; }

static constexpr int S2_32 = off2c(32);   // 43680 = sum (2l+1)^2, l<32
static constexpr int S2_16 = off2c(16);   // 5456

// ---- host blob layout (bytes) ----
static constexpr size_t B_LAM   = 0;                       // 1024 double (eigenvalues, packed l*l+b)
static constexpr size_t B_BETAS = 1024 * 8;                // 227 double
static constexpr size_t B_U     = B_BETAS + 227 * 8;       // 43680 float (packed eigvec mats)
static constexpr size_t B_PAC   = B_U + (size_t)S2_32 * 4; // 6*63 float
static constexpr size_t B_PAS   = B_PAC + 378 * 4;
static constexpr size_t B_PGC   = B_PAS + 378 * 4;
static constexpr size_t B_PGS   = B_PGC + 378 * 4;
static constexpr size_t B_WB    = B_PGS + 378 * 4;         // 128
static constexpr size_t B_WH    = B_WB + 128 * 4;          // 64
static constexpr size_t B_WQ    = B_WH + 64 * 4;           // 32
static constexpr size_t B_WINT  = B_WQ + 32 * 4;           // 32
static constexpr size_t BLOB_BYTES = B_WINT + 32 * 4;      // 191800

__host__ __device__ constexpr size_t AL(size_t x) { return (x + 255) & ~(size_t)255; }

// ---- workspace layout ----
static constexpr size_t O_TRIG  = AL(BLOB_BYTES);                       // 227*1024 float2
static constexpr size_t O_WS2   = AL(O_TRIG + (size_t)227 * 1024 * 8);  // [128][1024] f
static constexpr size_t O_WIGH  = AL(O_WS2 + (size_t)128 * 1024 * 4);   // [64][S2_32] f
static constexpr size_t O_WIG16 = AL(O_WIGH + (size_t)64 * S2_32 * 4);  // [64][S2_16]
static constexpr size_t O_WIGQ  = AL(O_WIG16 + (size_t)64 * S2_16 * 4); // [32][S2_16]
static constexpr size_t O_D3    = AL(O_WIGQ + (size_t)32 * S2_16 * 4);  // [S2_32]
static constexpr size_t O_D4    = AL(O_D3 + (size_t)S2_32 * 4);         // [S2_16]
static constexpr size_t O_D5    = AL(O_D4 + (size_t)S2_16 * 4);
static constexpr size_t O_FEAT  = AL(O_D5 + (size_t)S2_16 * 4);         // 128 f
static constexpr size_t O_A0    = AL(O_FEAT + 512);
static constexpr size_t SZ_BIG  = 68ull << 20;
static constexpr size_t SZ_MED  = 24ull << 20;
static constexpr size_t O_A1    = O_A0 + SZ_BIG;
static constexpr size_t O_A2    = O_A1 + SZ_BIG;
static constexpr size_t O_A3    = O_A2 + SZ_MED;
static constexpr size_t O_A4    = O_A3 + SZ_MED;
static constexpr size_t WS_REQ  = O_A4 + SZ_MED;   // ~224 MiB

// ---------------------------------------------------------------- host tables
struct HostTables { std::vector<unsigned char> blob; };

static void jacobi_sym(int n, std::vector<double>& A, std::vector<double>& V, std::vector<double>& w) {
  V.assign((size_t)n * n, 0.0);
  for (int i = 0; i < n; i++) V[(size_t)i * n + i] = 1.0;
  for (int sweep = 0; sweep < 80; ++sweep) {
    double off = 0;
    for (int p = 0; p < n; p++)
      for (int q = p + 1; q < n; q++) off += A[(size_t)p * n + q] * A[(size_t)p * n + q];
    if (off < 1e-26) break;
    for (int p = 0; p < n - 1; p++) {
      for (int q = p + 1; q < n; q++) {
        double apq = A[(size_t)p * n + q];
        if (fabs(apq) < 1e-300) continue;
        double app = A[(size_t)p * n + p], aqq = A[(size_t)q * n + q];
        double theta = (aqq - app) / (2.0 * apq);
        double t = ((theta >= 0) ? 1.0 : -1.0) / (fabs(theta) + sqrt(theta * theta + 1.0));
        double c = 1.0 / sqrt(t * t + 1.0), s = t * c;
        for (int i = 0; i < n; i++) {
          double aip = A[(size_t)i * n + p], aiq = A[(size_t)i * n + q];
          A[(size_t)i * n + p] = c * aip - s * aiq;
          A[(size_t)i * n + q] = s * aip + c * aiq;
        }
        for (int i = 0; i < n; i++) {
          double api = A[(size_t)p * n + i], aqi = A[(size_t)q * n + i];
          A[(size_t)p * n + i] = c * api - s * aqi;
          A[(size_t)q * n + i] = s * api + c * aqi;
        }
        for (int i = 0; i < n; i++) {
          double vip = V[(size_t)i * n + p], viq = V[(size_t)i * n + q];
          V[(size_t)i * n + p] = c * vip - s * viq;
          V[(size_t)i * n + q] = s * vip + c * viq;
        }
      }
    }
  }
  for (int i = 0; i < n; i++) w[i] = A[(size_t)i * n + i];
}

static HostTables build_tables() {
  HostTables ht;
  ht.blob.assign(BLOB_BYTES, 0);
  double* lam  = (double*)(ht.blob.data() + B_LAM);
  double* bet  = (double*)(ht.blob.data() + B_BETAS);
  float*  U    = (float*)(ht.blob.data() + B_U);
  float*  PAc  = (float*)(ht.blob.data() + B_PAC);
  float*  PAs  = (float*)(ht.blob.data() + B_PAS);
  float*  PGc  = (float*)(ht.blob.data() + B_PGC);
  float*  PGs  = (float*)(ht.blob.data() + B_PGS);
  float*  wbf  = (float*)(ht.blob.data() + B_WB);
  float*  whf  = (float*)(ht.blob.data() + B_WH);
  float*  wqf  = (float*)(ht.blob.data() + B_WQ);
  float*  wint = (float*)(ht.blob.data() + B_WINT);

  auto dh = [](int b, std::vector<double>& beta, std::vector<double>& w) {
    beta.resize(2 * b); w.resize(2 * b);
    for (int k = 0; k < 2 * b; k++) {
      double bk = M_PI * (2 * k + 1) / (4.0 * b);
      beta[k] = bk;
      double s = 0;
      for (int j = 0; j < b; j++) s += sin((2 * j + 1) * bk) / (2 * j + 1);
      w[k] = (2.0 / b) * sin(bk) * s;
    }
  };
  std::vector<double> bb, wb64, bh, wh32, bq, wq16;
  dh(64, bb, wb64); dh(32, bh, wh32); dh(16, bq, wq16);
  for (int k = 0; k < 128; k++) { bet[k] = bb[k]; wbf[k] = (float)wb64[k]; }
  for (int k = 0; k < 64; k++)  { bet[128 + k] = bh[k]; whf[k] = (float)wh32[k]; }
  for (int k = 0; k < 32; k++)  { bet[192 + k] = bq[k]; wqf[k] = (float)wq16[k]; }
  bet[224] = M_PI / 16.0; bet[225] = M_PI / 8.0; bet[226] = M_PI / 4.0;
  double sq = 0; for (int k = 0; k < 32; k++) sq += wq16[k];
  for (int k = 0; k < 32; k++) wint[k] = (float)(wq16[k] / (sq * 1024.0));

  // eigensystems: B real symm tridiag, zero diag, offdiag -c_j/2 (see D=diag(i^j) transform of exp(beta K))
  std::vector<double> A, V, w;
  for (int l = 0; l < 32; l++) {
    int n = 2 * l + 1;
    A.assign((size_t)n * n, 0.0);
    for (int j = 0; j < n - 1; j++) {
      double mj = -l + j;
      double c = sqrt((double)l * (l + 1) - mj * (mj + 1));
      A[(size_t)j * n + j + 1] = -c / 2.0;
      A[(size_t)(j + 1) * n + j] = -c / 2.0;
    }
    w.assign(n, 0.0);
    jacobi_sym(n, A, V, w);
    for (int r = 0; r < n; r++)
      for (int b2 = 0; b2 < n; b2++) U[off2c(l) + r * n + b2] = (float)V[(size_t)r * n + b2];
    for (int b2 = 0; b2 < n; b2++) lam[l * l + b2] = (double)llround(w[b2]); // Jy spectrum is exactly -l..l
  }
  for (int a = 0; a < 6; a++) {
    double al = 2.0 * M_PI * a / 6.0;
    for (int mi = 0; mi < 63; mi++) { int m = mi - 31; PAc[a * 63 + mi] = (float)cos(m * al); PAs[a * 63 + mi] = (float)sin(m * al); }
  }
  for (int c = 0; c < 6; c++) {
    double ga = -2.0 * M_PI + 4.0 * M_PI * c / 5.0;  // linspace(-2pi, 2pi, 6)
    for (int mi = 0; mi < 63; mi++) { int m = mi - 31; PGc[c * 63 + mi] = (float)cos(m * ga); PGs[c * 63 + mi] = (float)sin(m * ga); }
  }
  return ht;
}

// ---------------------------------------------------------------- device helpers
#define DEVFN static __device__ __forceinline__
DEVFN int isqrt_i(int p) {
  int l = (int)sqrtf((float)p);
  while (l * l > p) --l;
  while ((l + 1) * (l + 1) <= p) ++l;
  return l;
}
DEVFN float2 cmul(float2 a, float2 b) {
  return make_float2(a.x * b.x - a.y * b.y, a.x * b.y + a.y * b.x);
}
DEVFN void cmul_acc(float2& acc, float2 a, float2 w) {
  acc.x += a.x * w.x - a.y * w.y;
  acc.y += a.x * w.y + a.y * w.x;
}
DEVFN void crot(float2& w, float2 st) {
  float nx = w.x * st.x - w.y * st.y;
  w.y = w.x * st.y + w.y * st.x;
  w.x = nx;
}

// ---------------------------------------------------------------- kernels
// trig tables: cos/sin(beta * lambda) for every (beta row, packed l*l+b)
__global__ void k_trig(const double* __restrict__ lam, const double* __restrict__ betas, float2* __restrict__ trig) {
  int id = blockIdx.x * blockDim.x + threadIdx.x;
  if (id >= 227 * 1024) return;
  int row = id >> 10, p = id & 1023;
  double a = betas[row] * lam[p];
  double s, c;
  sincos(a, &s, &c);
  trig[id] = make_float2((float)c, (float)s);
}

// W_s2[k][l*l+mi] = d^l_{m0}(beta_b[k]) * wb[k]
__global__ void k_ws2(const float* __restrict__ U, const float2* __restrict__ Tb, const float* __restrict__ wb, float* __restrict__ W) {
  int id = blockIdx.x * blockDim.x + threadIdx.x;
  if (id >= 128 * 1024) return;
  int k = id >> 10, p = id & 1023;
  int l = isqrt_i(p); int mi = p - l * l; int n = 2 * l + 1;
  const float* Ul = U + off2c(l);
  const float2* T = Tb + (size_t)k * 1024 + l * l;
  float ac = 0, as = 0;
  for (int b = 0; b < n; b++) { float uu = Ul[mi * n + b] * Ul[l * n + b]; ac += uu * T[b].x; as += uu * T[b].y; }
  int q = (mi - l) & 3;
  float v = (q & 1) ? as : ac; if (q & 2) v = -v;
  W[id] = v * wb[k];
}

// generic packed wigner-d build: out[k][off2(l)+r*(2l+1)+c] = d^l_{rc}(beta_k)
__global__ void k_wig(const float* __restrict__ U, const float2* __restrict__ trig, float* __restrict__ out, int S2L) {
  int l = blockIdx.y, k = blockIdx.z;
  int n = 2 * l + 1;
  int t = blockIdx.x * blockDim.x + threadIdx.x;
  if (t >= n * n) return;
  int r = t / n, c = t - r * n;
  const float* Ul = U + off2c(l);
  const float2* T = trig + (size_t)k * 1024 + l * l;
  float ac = 0, as = 0;
  for (int b = 0; b < n; b++) { float uu = Ul[r * n + b] * Ul[c * n + b]; ac += uu * T[b].x; as += uu * T[b].y; }
  int q = (r - c) & 3;
  float v = (q & 1) ? as : ac; if (q & 2) v = -v;
  out[(size_t)k * S2L + off2c(l) + t] = v;
}

// 1x1 conv + relu: h1[z,o,hw]
__global__ void k_conv1(const float* __restrict__ x, const float* __restrict__ w1, const float* __restrict__ b1, float* __restrict__ h1) {
  int id = blockIdx.x * blockDim.x + threadIdx.x;
  if (id >= 2 * 16 * 16384) return;
  int hw = id & 16383; int zo = id >> 14; int o = zo & 15; int z = zo >> 4;
  float acc = b1[o];
  for (int c = 0; c < 4; c++) acc += w1[o * 4 + c] * x[(size_t)(z * 4 + c) * 16384 + hw];
  h1[id] = fmaxf(acc, 0.f);
}

// alpha-DFT (layer2): per block 4 rows staged in LDS; 4-chain rotator recurrence (ILP)
__global__ void k_dft_a(const float* __restrict__ h1, float2* __restrict__ xf) {
  __shared__ float rows[4][128];
  int tid = threadIdx.x;
  int r0 = blockIdx.x * 4;
  for (int idx = tid; idx < 4 * 128; idx += 256) rows[idx >> 7][idx & 127] = h1[(size_t)r0 * 128 + idx];
  __syncthreads();
  int r = tid >> 6;         // 0..3
  int j = tid & 63;         // 0..63; j<63 active
  if (j >= 63) return;
  float as = -6.28318530717958647692f * (float)(j - 31) / 128.f;
  float2 st; __sincosf(as, &st.y, &st.x);
  float2 q0 = make_float2(1.f, 0.f), q1 = st, q2 = cmul(q1, st), q3 = cmul(q2, st);
  float2 st2 = cmul(st, st), st4 = cmul(st2, st2);
  float2 a0 = make_float2(0.f, 0.f), a1 = a0, a2 = a0, a3 = a0;
  const float* row = rows[r];
  for (int a = 0; a < 128; a += 4) {
    float h0 = row[a], h1v = row[a + 1], h2 = row[a + 2], h3 = row[a + 3];
    a0.x += h0 * q0.x; a0.y += h0 * q0.y; crot(q0, st4);
    a1.x += h1v * q1.x; a1.y += h1v * q1.y; crot(q1, st4);
    a2.x += h2 * q2.x; a2.y += h2 * q2.y; crot(q2, st4);
    a3.x += h3 * q3.x; a3.y += h3 * q3.y; crot(q3, st4);
  }
  float2 acc = make_float2(a0.x + a1.x + a2.x + a3.x, a0.y + a1.y + a2.y + a3.y);
  xf[(size_t)(r0 + r) * 63 + j] = make_float2(acc.x / 128.f, acc.y / 128.f);
}

// X2[zi][l*l+mi] = sum_k Ws2[k][p] * xf2[zi,k,jm]
__global__ void k_x2(const float* __restrict__ W, const float2* __restrict__ xf, float2* __restrict__ X) {
  int id = blockIdx.x * blockDim.x + threadIdx.x;
  if (id >= 2 * 16 * 1024) return;
  int p = id & 1023; int zi = id >> 10;
  int l = isqrt_i(p); int mi = p - l * l; int jm = mi - l + 31;
  float2 acc = make_float2(0.f, 0.f);
  for (int k = 0; k < 128; k++) {
    float w = W[(size_t)k * 1024 + p];
    float2 v = xf[((size_t)zi * 128 + k) * 63 + jm];
    acc.x += w * v.x; acc.y += w * v.y;
  }
  X[id] = acc;
}

// kappa2[i*16+o][j] = sum_a k2[i,o,a] e^{i (j-31) alpha_a}
__global__ void k_kap2(const float* __restrict__ k2, const float* __restrict__ PAc, const float* __restrict__ PAs, float2* __restrict__ kap) {
  int id = blockIdx.x * blockDim.x + threadIdx.x;
  if (id >= 16 * 16 * 63) return;
  int j = id % 63; int io = id / 63;
  float2 acc = make_float2(0.f, 0.f);
  for (int a = 0; a < 6; a++) {
    float kv = k2[io * 6 + a];
    acc.x += kv * PAc[a * 63 + j]; acc.y += kv * PAs[a * 63 + j];
  }
  kap[id] = acc;
}

// Y2[z,o,pk] = sum_i X2[z,i,l*l+mi] * conj(d^l_{n0} kappa2[i,o,jn])
__global__ void k_y2(const float2* __restrict__ X, const float2* __restrict__ kap, const float* __restrict__ d3, float2* __restrict__ Y) {
  int l = blockIdx.y; int n21 = 2 * l + 1;
  int t = blockIdx.x * blockDim.x + threadIdx.x;
  if (t >= n21 * n21) return;
  int zo = blockIdx.z; int o = zo & 15; int z = zo >> 4;
  int mi = t / n21, ni = t - mi * n21;
  float dv = d3[off2c(l) + ni * n21 + l];
  int jn = ni - l + 31;
  float2 acc = make_float2(0.f, 0.f);
  for (int i = 0; i < 16; i++) {
    float2 xv = X[(size_t)(z * 16 + i) * 1024 + l * l + mi];
    float2 kv = kap[(size_t)(i * 16 + o) * 63 + jn];
    acc.x += dv * (xv.x * kv.x + xv.y * kv.y);
    acc.y += dv * (xv.y * kv.x - xv.x * kv.y);
  }
  Y[(size_t)(z * 16 + o) * S2_32 + off2c(l) + t] = acc;
}

// ---------------------------------------------------------------- k_y as fused complex GEMM (v1 — verified, 0 bank conflicts)
// Y[z,o,l,mi,ni] = sum_{i,p} X[z,i,l,mi,p] * (d^l[ni,p] * conj(kap[i,o,jn,jp]))
// GEMM per (z,l): M=n21 (mi), N=CO*n21 (o,ni), K=CI*n21 (i,p); B built on the fly.
template <int CI, int CO, int L>
__global__ __launch_bounds__(256) void k_y_gemm(const float2* __restrict__ X, const float2* __restrict__ kap,
                                                const float* __restrict__ dtab, float2* __restrict__ Y, int S2L) {
  constexpr int NF = 2 * L - 1;
  constexpr int BM = 32, BN = 64, BK = 32;
  const int l = blockIdx.y;
  const int n21 = 2 * l + 1;
  const int Kdim = CI * n21;
  const int N = CO * n21;
  const int ntn = (N + BN - 1) / BN;
  const int ntm = (n21 + BM - 1) / BM;
  if ((int)blockIdx.x >= ntm * ntn) return;
  const int tm = blockIdx.x / ntn, tn = blockIdx.x % ntn;
  const int z = blockIdx.z;
  const int off = off2c(l);
  const float2* Xz = X + (size_t)z * CI * S2L + off;
  float2* Yz = Y + (size_t)z * CO * S2L + off;
  const float* dl = dtab + off;

  __shared__ float2 As[BM][BK + 1];
  __shared__ float2 Bs[BK][BN + 1];
  __shared__ int nLUT_o[BN];
  __shared__ short nLUT_ni[BN];

  const int tid = threadIdx.x;
  if (tid < BN) {
    int ng = tn * BN + tid;
    int o = ng / n21;
    nLUT_o[tid] = (ng < N) ? o : -1;
    nLUT_ni[tid] = (short)(ng - o * n21);
  }
  const int kk = tid & 31;   // load lane: K index within tile (fixed per thread)
  const int rr = tid >> 5;   // 0..7
  const int mrow = tid >> 4; // 0..15 compute row base
  const int ncol = tid & 15; // compute col base
  float2 acc[2][4];
  #pragma unroll
  for (int a = 0; a < 2; a++)
    #pragma unroll
    for (int b = 0; b < 4; b++) acc[a][b] = make_float2(0.f, 0.f);
  __syncthreads();

  for (int k0 = 0; k0 < Kdim; k0 += BK) {
    int kg = k0 + kk;
    int i = (unsigned)kg / (unsigned)n21;
    int p = kg - i * n21;
    bool kok = kg < Kdim;
    // A fill: As[m][kk] = X[z,i,mi,p]
    #pragma unroll
    for (int s = 0; s < 4; s++) {
      int m = rr + s * 8;
      int mg = tm * BM + m;
      float2 v = make_float2(0.f, 0.f);
      if (kok && mg < n21) v = Xz[(size_t)i * S2L + mg * n21 + p];
      As[m][kk] = v;
    }
    // B fill: Bs[kk][nn] = d[ni,p] * conj(kap[i,o,jn,jp])
    int jp = p - l + (L - 1);
    #pragma unroll
    for (int s = 0; s < 8; s++) {
      int nn = rr + s * 8;
      float2 v = make_float2(0.f, 0.f);
      int o = nLUT_o[nn];
      if (kok && o >= 0) {
        int ni = nLUT_ni[nn];
        float dv = dl[ni * n21 + p];
        int jn = ni - l + (L - 1);
        float2 kv = kap[(size_t)(i * CO + o) * NF * NF + jn * NF + jp];
        v = make_float2(dv * kv.x, -dv * kv.y);
      }
      Bs[kk][nn] = v;
    }
    __syncthreads();
    #pragma unroll
    for (int q = 0; q < BK; q++) {
      float2 a0 = As[mrow][q];
      float2 a1 = As[mrow + 16][q];
      #pragma unroll
      for (int j = 0; j < 4; j++) {
        float2 b = Bs[q][ncol + j * 16];
        acc[0][j].x += a0.x * b.x - a0.y * b.y;
        acc[0][j].y += a0.x * b.y + a0.y * b.x;
        acc[1][j].x += a1.x * b.x - a1.y * b.y;
        acc[1][j].y += a1.x * b.y + a1.y * b.x;
      }
    }
    __syncthreads();
  }
  #pragma unroll
  for (int sm = 0; sm < 2; sm++) {
    int mg = tm * BM + mrow + sm * 16;
    if (mg >= n21) continue;
    #pragma unroll
    for (int j = 0; j < 4; j++) {
      int nn = ncol + j * 16;
      int o = nLUT_o[nn];
      if (o < 0) continue;
      int ni = nLUT_ni[nn];
      Yz[(size_t)o * S2L + mg * n21 + ni] = acc[sm][j];
    }
  }
}

// F[zc,k,jm,jn] = sum_l (2l+1) * wig[k][pk] * Y[zc][pk]  (dense in (jm,jn))
__global__ void k_f(const float* __restrict__ wig, const float2* __restrict__ Y, float2* __restrict__ F,
                    int nzc, int NK, int L, int S2L) {
  int NF = 2 * L - 1;
  size_t id = (size_t)blockIdx.x * blockDim.x + threadIdx.x;
  size_t tot = (size_t)nzc * NK * NF * NF;
  if (id >= tot) return;
  int jn = (int)(id % NF); size_t r1 = id / NF;
  int jm = (int)(r1 % NF); size_t r2 = r1 / NF;
  int k = (int)(r2 % NK); int zc = (int)(r2 / NK);
  int m = jm - (L - 1), n = jn - (L - 1);
  int am = m < 0 ? -m : m, an = n < 0 ? -n : n;
  int lmin = am > an ? am : an;
  float2 acc = make_float2(0.f, 0.f);
  const float* wk = wig + (size_t)k * S2L;
  const float2* Yc = Y + (size_t)zc * S2L;
  for (int l = lmin; l < L; l++) {
    int n21 = 2 * l + 1;
    int pk = off2c(l) + (m + l) * n21 + (n + l);
    float w = wk[pk] * (float)n21;
    float2 yv = Yc[pk];
    acc.x += w * yv.x; acc.y += w * yv.y;
  }
  F[id] = acc;
}

// fused 2-stage inverse DFT  F[zc,k,:,:] -> h[zc,k,u,v] (+bias, relu)
// F staged in LDS (broadcast reads), 4-chain rotator recurrence (4x ILP on the serial twiddle chain).
template <int L, int B2>
__global__ void k_synth(const float2* __restrict__ F, const float* __restrict__ bias, float* __restrict__ h, int C, int NK) {
  constexpr int NF = 2 * L - 1;
  constexpr float TWO_PI = 6.28318530717958647692f;
  __shared__ float2 Ft[NF * NF];
  __shared__ float2 Gt[NF * B2];
  int bid = blockIdx.x;         // zc*NK + k
  int zc = bid / NK;
  int c = zc % C;
  int tid = threadIdx.x, nt = blockDim.x;
  const float2* Fb = F + (size_t)bid * NF * NF;
  for (int idx = tid; idx < NF * NF; idx += nt) Ft[idx] = Fb[idx];
  __syncthreads();
  // stage 1: Gt[jm][v] = sum_jn Ft[jm][jn] * e^{+i 2pi v (jn-(L-1))/B2}
  {
    int v = tid & (B2 - 1);    // invariant across idx iterations (nt % B2 == 0)
    float a0 = TWO_PI * (float)(((-(L - 1) * v) % B2 + B2) % B2) / (float)B2;
    float as = TWO_PI * (float)v / (float)B2;
    float2 w0, st;
    __sincosf(a0, &w0.y, &w0.x);
    __sincosf(as, &st.y, &st.x);
    float2 wi0 = w0, wi1 = cmul(w0, st), wi2 = cmul(wi1, st), wi3 = cmul(wi2, st);
    float2 st2 = cmul(st, st), st4 = cmul(st2, st2);
    for (int idx = tid; idx < NF * B2; idx += nt) {
      int jm = idx / B2;
      const float2* Fr = Ft + jm * NF;
      float2 c0 = make_float2(0.f, 0.f), c1 = c0, c2 = c0, c3 = c0;
      float2 q0 = wi0, q1 = wi1, q2 = wi2, q3 = wi3;
      int jn = 0;
      for (; jn + 4 <= NF; jn += 4) {
        cmul_acc(c0, Fr[jn], q0); crot(q0, st4);
        cmul_acc(c1, Fr[jn + 1], q1); crot(q1, st4);
        cmul_acc(c2, Fr[jn + 2], q2); crot(q2, st4);
        cmul_acc(c3, Fr[jn + 3], q3); crot(q3, st4);
      }
      if (jn < NF) cmul_acc(c0, Fr[jn], q0);           // NF%4==3 tail
      if (jn + 1 < NF) cmul_acc(c1, Fr[jn + 1], q1);
      if (jn + 2 < NF) cmul_acc(c2, Fr[jn + 2], q2);
      Gt[idx] = make_float2(c0.x + c1.x + c2.x + c3.x, c0.y + c1.y + c2.y + c3.y);
    }
  }
  __syncthreads();
  float bv = bias[c];
  float* hb = h + (size_t)bid * B2 * B2;
  for (int idx = tid; idx < B2 * B2; idx += nt) {
    int u = idx / B2, v = idx & (B2 - 1);
    float a0 = TWO_PI * (float)(((-(L - 1) * u) % B2 + B2) % B2) / (float)B2;
    float as = TWO_PI * (float)u / (float)B2;
    float2 w0, st;
    __sincosf(a0, &w0.y, &w0.x);
    __sincosf(as, &st.y, &st.x);
    float2 q0 = w0, q1 = cmul(w0, st), q2 = cmul(q1, st), q3 = cmul(q2, st);
    float2 st2 = cmul(st, st), st4 = cmul(st2, st2);
    float r0 = 0, r1 = 0, r2 = 0, r3 = 0;
    int jm = 0;
    for (; jm + 4 <= NF; jm += 4) {
      float2 g0 = Gt[jm * B2 + v], g1 = Gt[(jm + 1) * B2 + v];
      float2 g2 = Gt[(jm + 2) * B2 + v], g3 = Gt[(jm + 3) * B2 + v];
      r0 += g0.x * q0.x - g0.y * q0.y; crot(q0, st4);
      r1 += g1.x * q1.x - g1.y * q1.y; crot(q1, st4);
      r2 += g2.x * q2.x - g2.y * q2.y; crot(q2, st4);
      r3 += g3.x * q3.x - g3.y * q3.y; crot(q3, st4);
    }
    if (jm < NF)     { float2 g = Gt[jm * B2 + v];       r0 += g.x * q0.x - g.y * q0.y; }
    if (jm + 1 < NF) { float2 g = Gt[(jm + 1) * B2 + v]; r1 += g.x * q1.x - g.y * q1.y; }
    if (jm + 2 < NF) { float2 g = Gt[(jm + 2) * B2 + v]; r2 += g.x * q2.x - g.y * q2.y; }
    hb[idx] = fmaxf(r0 + r1 + r2 + r3 + bv, 0.f);
  }
}

// fused 2-stage forward DFT: h[zc,k,:,:] -> xf[zc,k,jm,jn] (truncated, /B2^2)
// h staged in LDS; Tt split re/im; 4-chain rotator recurrence.
template <int L, int B2>
__global__ void k_fwd(const float* __restrict__ h, float2* __restrict__ xf) {
  constexpr int NF = 2 * L - 1;
  constexpr float TWO_PI = 6.28318530717958647692f;
  __shared__ float ht[B2 * B2];
  __shared__ float Ttr[B2 * NF];
  __shared__ float Tti[B2 * NF];
  int bid = blockIdx.x;
  int tid = threadIdx.x, nt = blockDim.x;
  const float* hb = h + (size_t)bid * B2 * B2;
  for (int idx = tid; idx < B2 * B2; idx += nt) ht[idx] = hb[idx];
  __syncthreads();
  for (int idx = tid; idx < B2 * NF; idx += nt) {
    int u = idx / NF, jn = idx - u * NF;
    float as = -TWO_PI * (float)(jn - (L - 1)) / (float)B2;
    float2 st;
    __sincosf(as, &st.y, &st.x);
    float2 q0 = make_float2(1.f, 0.f), q1 = st, q2 = cmul(q1, st), q3 = cmul(q2, st);
    float2 st2 = cmul(st, st), st4 = cmul(st2, st2);
    float2 a0 = make_float2(0.f, 0.f), a1 = a0, a2 = a0, a3 = a0;
    const float* hr = ht + u * B2;
    for (int v = 0; v < B2; v += 4) {     // B2 % 4 == 0
      float h0 = hr[v], h1v = hr[v + 1], h2 = hr[v + 2], h3 = hr[v + 3];
      a0.x += h0 * q0.x; a0.y += h0 * q0.y; crot(q0, st4);
      a1.x += h1v * q1.x; a1.y += h1v * q1.y; crot(q1, st4);
      a2.x += h2 * q2.x; a2.y += h2 * q2.y; crot(q2, st4);
      a3.x += h3 * q3.x; a3.y += h3 * q3.y; crot(q3, st4);
    }
    Ttr[idx] = a0.x + a1.x + a2.x + a3.x;
    Tti[idx] = a0.y + a1.y + a2.y + a3.y;
  }
  __syncthreads();
  float2* xb = xf + (size_t)bid * NF * NF;
  const float inv = 1.f / ((float)B2 * (float)B2);
  for (int idx = tid; idx < NF * NF; idx += nt) {
    int jm = idx / NF, jn = idx - jm * NF;
    float as = -TWO_PI * (float)(jm - (L - 1)) / (float)B2;
    float2 st;
    __sincosf(as, &st.y, &st.x);
    float2 q0 = make_float2(1.f, 0.f), q1 = st, q2 = cmul(q1, st), q3 = cmul(q2, st);
    float2 st2 = cmul(st, st), st4 = cmul(st2, st2);
    float2 a0 = make_float2(0.f, 0.f), a1 = a0, a2 = a0, a3 = a0;
    for (int u = 0; u < B2; u += 4) {     // B2 % 4 == 0
      float2 t0 = make_float2(Ttr[u * NF + jn], Tti[u * NF + jn]);
      float2 t1 = make_float2(Ttr[(u + 1) * NF + jn], Tti[(u + 1) * NF + jn]);
      float2 t2 = make_float2(Ttr[(u + 2) * NF + jn], Tti[(u + 2) * NF + jn]);
      float2 t3 = make_float2(Ttr[(u + 3) * NF + jn], Tti[(u + 3) * NF + jn]);
      cmul_acc(a0, t0, q0); crot(q0, st4);
      cmul_acc(a1, t1, q1); crot(q1, st4);
      cmul_acc(a2, t2, q2); crot(q2, st4);
      cmul_acc(a3, t3, q3); crot(q3, st4);
    }
    xb[idx] = make_float2((a0.x + a1.x + a2.x + a3.x) * inv, (a0.y + a1.y + a2.y + a3.y) * inv);
  }
}

// X[zi][pk] = sum_k wgt[k] * wig[k][pk] * xf[zi,k,jm,jn]
__global__ void k_xc(const float* __restrict__ wig, const float* __restrict__ wgt, const float2* __restrict__ xf,
                     float2* __restrict__ X, int NK, int L, int S2L) {
  int NF = 2 * L - 1;
  int l = blockIdx.y; int n21 = 2 * l + 1;
  int t = blockIdx.x * blockDim.x + threadIdx.x;
  if (t >= n21 * n21) return;
  int zi = blockIdx.z;
  int mi = t / n21, ni = t - mi * n21;
  int jm = mi - l + (L - 1), jn = ni - l + (L - 1);
  int pk = off2c(l) + t;
  float2 acc = make_float2(0.f, 0.f);
  for (int k = 0; k < NK; k++) {
    float w = wig[(size_t)k * S2L + pk] * wgt[k];
    float2 v = xf[((size_t)zi * NK + k) * NF * NF + jm * NF + jn];
    acc.x += w * v.x; acc.y += w * v.y;
  }
  X[(size_t)zi * S2L + pk] = acc;
}

// kappa[io][jn][jp] = sum_{a,c} ker[io,a*6+c] e^{i m_n alpha_a} e^{i m_p gamma_c}
__global__ void k_kap(const float* __restrict__ ker, const float* __restrict__ PAc, const float* __restrict__ PAs,
                      const float* __restrict__ PGc, const float* __restrict__ PGs,
                      float2* __restrict__ kap, int NIO, int NF, int poff) {
  int id = blockIdx.x * blockDim.x + threadIdx.x;
  if (id >= NIO * NF * NF) return;
  int jp = id % NF; int r = id / NF; int jn = r % NF; int io = r / NF;
  float2 acc = make_float2(0.f, 0.f);
  for (int a = 0; a < 6; a++) {
    float pac = PAc[a * 63 + jn + poff], pas = PAs[a * 63 + jn + poff];
    for (int c = 0; c < 6; c++) {
      float kv = ker[io * 36 + a * 6 + c];
      float pgc = PGc[c * 63 + jp + poff], pgs = PGs[c * 63 + jp + poff];
      acc.x += kv * (pac * pgc - pas * pgs);
      acc.y += kv * (pac * pgs + pas * pgc);
    }
  }
  kap[id] = acc;
}

// feat[zc] = sum_{beta,u,v} h5[zc,beta,u,v] * wint[beta]
__global__ void k_feat(const float* __restrict__ h5, const float* __restrict__ wint, float* __restrict__ feat) {
  __shared__ float red[256];
  int zc = blockIdx.x;
  const float* hb = h5 + (size_t)zc * 32768;
  float acc = 0;
  for (int idx = threadIdx.x; idx < 32768; idx += 256) acc += hb[idx] * wint[idx >> 10];
  red[threadIdx.x] = acc;
  __syncthreads();
  for (int s = 128; s > 0; s >>= 1) { if (threadIdx.x < s) red[threadIdx.x] += red[threadIdx.x + s]; __syncthreads(); }
  if (threadIdx.x == 0) feat[zc] = red[0];
}

// MLP head per batch row
__global__ void k_head(const float* __restrict__ feat, const float* __restrict__ m, const float* __restrict__ wm,
                       const float* __restrict__ bm, const float* __restrict__ wl1, const float* __restrict__ bl1,
                       const float* __restrict__ wl2, const float* __restrict__ bl2, float* __restrict__ out) {
  __shared__ float zin[68];
  __shared__ float red[512];
  int z = blockIdx.x, tid = threadIdx.x;
  if (tid < 64) zin[tid] = feat[z * 64 + tid];
  else if (tid < 68) zin[tid] = fmaxf(m[z] * wm[tid - 64] + bm[tid - 64], 0.f);
  __syncthreads();
  float part = 0;
  for (int q = tid; q < 500; q += 512) {
    float acc = bl1[q];
    for (int j = 0; j < 68; j++) acc += zin[j] * wl1[q * 68 + j];
    part += fmaxf(acc, 0.f) * wl2[q];
  }
  red[tid] = part;
  __syncthreads();
  for (int s = 256; s > 0; s >>= 1) { if (tid < s) red[tid] += red[tid + s]; __syncthreads(); }
  if (tid == 0) out[z] = red[0] + bl2[0];
}

// ---------------------------------------------------------------- launch
extern "C" void kernel_launch(void* const* d_in, const int* in_sizes, int n_in,
                              void* d_out, int out_size, void* d_ws, size_t ws_size,
                              hipStream_t stream) {
  static HostTables HT = build_tables();  // host-only, once

  if (ws_size < WS_REQ) {
    fprintf(stderr, "[s2cnn] ws too small: need %zu bytes, got %zu\n", (size_t)WS_REQ, ws_size);
    return;
  }
  if (n_in < 18) { fprintf(stderr, "[s2cnn] bad n_in %d\n", n_in); return; }

  const float* x   = (const float*)d_in[0];
  const float* mI  = (const float*)d_in[1];
  const float* w1  = (const float*)d_in[2];
  const float* b1  = (const float*)d_in[3];
  const float* k2  = (const float*)d_in[4];
  const float* bb2 = (const float*)d_in[5];
  const float* k3  = (const float*)d_in[6];
  const float* bb3 = (const float*)d_in[7];
  const float* k4  = (const float*)d_in[8];
  const float* bb4 = (const float*)d_in[9];
  const float* k5  = (const float*)d_in[10];
  const float* bb5 = (const float*)d_in[11];
  const float* wm  = (const float*)d_in[12];
  const float* bm  = (const float*)d_in[13];
  const float* wl1 = (const float*)d_in[14];
  const float* bl1 = (const float*)d_in[15];
  const float* wl2 = (const float*)d_in[16];
  const float* bl2 = (const float*)d_in[17];
  float* out = (float*)d_out;

  char* ws = (char*)d_ws;
  // upload constant blob (192 KB)
  hipMemcpyAsync(ws, HT.blob.data(), BLOB_BYTES, hipMemcpyHostToDevice, stream);

  const double* dLam  = (const double*)(ws + B_LAM);
  const double* dBet  = (const double*)(ws + B_BETAS);
  const float*  dU    = (const float*)(ws + B_U);
  const float*  dPAc  = (const float*)(ws + B_PAC);
  const float*  dPAs  = (const float*)(ws + B_PAS);
  const float*  dPGc  = (const float*)(ws + B_PGC);
  const float*  dPGs  = (const float*)(ws + B_PGS);
  const float*  dWb   = (const float*)(ws + B_WB);
  const float*  dWh   = (const float*)(ws + B_WH);
  const float*  dWq   = (const float*)(ws + B_WQ);
  const float*  dWint = (const float*)(ws + B_WINT);

  float2* TRIG = (float2*)(ws + O_TRIG);
  float2* Tb = TRIG;                 // 128 rows
  float2* Th = TRIG + (size_t)128 * 1024;
  float2* Tq = TRIG + (size_t)192 * 1024;
  float2* Ts16 = TRIG + (size_t)224 * 1024;
  float2* Ts8  = TRIG + (size_t)225 * 1024;
  float2* Ts4  = TRIG + (size_t)226 * 1024;
  float* WS2   = (float*)(ws + O_WS2);
  float* WIGH  = (float*)(ws + O_WIGH);
  float* WIG16 = (float*)(ws + O_WIG16);
  float* WIGQ  = (float*)(ws + O_WIGQ);
  float* D3    = (float*)(ws + O_D3);
  float* D4    = (float*)(ws + O_D4);
  float* D5    = (float*)(ws + O_D5);
  float* FEAT  = (float*)(ws + O_FEAT);
  char* A0 = ws + O_A0;
  char* A1 = ws + O_A1;
  char* A2 = ws + O_A2;
  char* A3 = ws + O_A3;
  char* A4 = ws + O_A4;

  // ---- build tables on device (cheap, every call: ws is re-poisoned)
  k_trig<<<(227 * 1024 + 255) / 256, 256, 0, stream>>>(dLam, dBet, TRIG);
  k_ws2<<<(128 * 1024 + 255) / 256, 256, 0, stream>>>(dU, Tb, dWb, WS2);
  k_wig<<<dim3(16, 32, 64), 256, 0, stream>>>(dU, Th, WIGH, S2_32);
  k_wig<<<dim3(4, 16, 64), 256, 0, stream>>>(dU, Th, WIG16, S2_16);
  k_wig<<<dim3(4, 16, 32), 256, 0, stream>>>(dU, Tq, WIGQ, S2_16);
  k_wig<<<dim3(16, 32, 1), 256, 0, stream>>>(dU, Ts16, D3, S2_32);
  k_wig<<<dim3(4, 16, 1), 256, 0, stream>>>(dU, Ts8, D4, S2_16);
  k_wig<<<dim3(4, 16, 1), 256, 0, stream>>>(dU, Ts4, D5, S2_16);

  // ---- layer 1: 1x1 conv + relu -> h1 (A2)
  float* h1 = (float*)A2;
  k_conv1<<<(2 * 16 * 16384 + 255) / 256, 256, 0, stream>>>(x, w1, b1, h1);

  // ---- layer 2: s2 conv
  float2* xf2 = (float2*)A0;
  k_dft_a<<<2 * 16 * 128 / 4, 256, 0, stream>>>(h1, xf2);
  float2* X2 = (float2*)A3;
  k_x2<<<(2 * 16 * 1024 + 255) / 256, 256, 0, stream>>>(WS2, xf2, X2);
  float2* kap2 = (float2*)A4;
  k_kap2<<<(16 * 16 * 63 + 255) / 256, 256, 0, stream>>>(k2, dPAc, dPAs, kap2);
  float2* Y2 = (float2*)A1;
  k_y2<<<dim3(16, 32, 32), 256, 0, stream>>>(X2, kap2, D3, Y2);
  float2* F2 = (float2*)A0;
  k_f<<<(2 * 16 * 64 * 63 * 63 + 255) / 256, 256, 0, stream>>>(WIGH, Y2, F2, 32, 64, 32, S2_32);
  float* h2 = (float*)A1;
  k_synth<32, 64><<<2 * 16 * 64, 256, 0, stream>>>(F2, bb2, h2, 16, 64);

  // ---- layer 3: so3 conv (b=32, L=32)
  float2* xf3 = (float2*)A0;
  k_fwd<32, 64><<<2 * 16 * 64, 256, 0, stream>>>(h2, xf3);
  float2* X3 = (float2*)A2;
  k_xc<<<dim3(16, 32, 2 * 16), 256, 0, stream>>>(WIGH, dWh, xf3, X3, 64, 32, S2_32);
  float2* kap3 = (float2*)A3;
  k_kap<<<(16 * 32 * 63 * 63 + 255) / 256, 256, 0, stream>>>(k3, dPAc, dPAs, dPGc, dPGs, kap3, 16 * 32, 63, 0);
  float2* Y3 = (float2*)A4;
  k_y_gemm<16, 32, 32><<<dim3(64, 32, 2), 256, 0, stream>>>(X3, kap3, D3, Y3, S2_32);
  float* h3 = (float*)A1;
  for (int z = 0; z < 2; z++) {
    float2* F3 = (float2*)A0;
    k_f<<<(32 * 64 * 63 * 63 + 255) / 256, 256, 0, stream>>>(WIGH, Y3 + (size_t)z * 32 * S2_32, F3, 32, 64, 32, S2_32);
    k_synth<32, 64><<<32 * 64, 256, 0, stream>>>(F3, bb3, h3 + (size_t)z * 32 * 64 * 4096, 32, 64);
  }

  // ---- layer 4: so3 conv (b=32 -> 16, L=16)
  float2* xf4 = (float2*)A0;
  k_fwd<16, 64><<<2 * 32 * 64, 256, 0, stream>>>(h3, xf4);
  float2* X4 = (float2*)A2;
  k_xc<<<dim3(4, 16, 2 * 32), 256, 0, stream>>>(WIG16, dWh, xf4, X4, 64, 16, S2_16);
  float2* kap4 = (float2*)A3;
  k_kap<<<(32 * 32 * 31 * 31 + 255) / 256, 256, 0, stream>>>(k4, dPAc, dPAs, dPGc, dPGs, kap4, 32 * 32, 31, 16);
  float2* Y4 = (float2*)A4;
  k_y_gemm<32, 32, 16><<<dim3(16, 16, 2), 256, 0, stream>>>(X4, kap4, D4, Y4, S2_16);
  float2* F4 = (float2*)A1;
  k_f<<<(2 * 32 * 32 * 31 * 31 + 255) / 256, 256, 0, stream>>>(WIGQ, Y4, F4, 64, 32, 16, S2_16);
  float* h4 = (float*)A0;
  k_synth<16, 32><<<2 * 32 * 32, 256, 0, stream>>>(F4, bb4, h4, 32, 32);

  // ---- layer 5: so3 conv (b=16, L=16)
  float2* xf5 = (float2*)A1;
  k_fwd<16, 32><<<2 * 32 * 32, 256, 0, stream>>>(h4, xf5);
  float2* X5 = (float2*)A2;
  k_xc<<<dim3(4, 16, 2 * 32), 256, 0, stream>>>(WIGQ, dWq, xf5, X5, 32, 16, S2_16);
  float2* kap5 = (float2*)A3;
  k_kap<<<(32 * 64 * 31 * 31 + 255) / 256, 256, 0, stream>>>(k5, dPAc, dPAs, dPGc, dPGs, kap5, 32 * 64, 31, 16);
  float2* Y5 = (float2*)A4;
  k_y_gemm<32, 64, 16><<<dim3(31, 16, 2), 256, 0, stream>>>(X5, kap5, D5, Y5, S2_16);
  float2* F5 = (float2*)A0;
  k_f<<<(2 * 64 * 32 * 31 * 31 + 255) / 256, 256, 0, stream>>>(WIGQ, Y5, F5, 128, 32, 16, S2_16);
  float* h5 = (float*)A1;
  k_synth<16, 32><<<2 * 64 * 32, 256, 0, stream>>>(F5, bb5, h5, 64, 32);

  // ---- head
  k_feat<<<128, 256, 0, stream>>>(h5, dWint, FEAT);
  k_head<<<2, 512, 0, stream>>>(FEAT, mI, wm, bm, wl1, bl1, wl2, bl2, out);
}

// Round 9
// 5344.531 us; speedup vs baseline: 1.8065x; 1.7080x over previous
//
#include <hip/hip_runtime.h>
#include <cstdio>
#include <cmath>
#include <cstring>
#include <vector>

#ifndef M_PI
#define M_PI 3.14159265358979323846
#endif

// ---------------------------------------------------------------- constants
__host__ __device__ constexpr int off2c(int l) { return l * (2 * l - 1) * (2 * l + 1) / 3; }

static constexpr int S2_32 = off2c(32);   // 43680 = sum (2l+1)^2, l<32
static constexpr int S2_16 = off2c(16);   // 5456

// ---- host blob layout (bytes) ----
static constexpr size_t B_LAM   = 0;                       // 1024 double (eigenvalues, packed l*l+b)
static constexpr size_t B_BETAS = 1024 * 8;                // 227 double
static constexpr size_t B_U     = B_BETAS + 227 * 8;       // 43680 float (packed eigvec mats)
static constexpr size_t B_PAC   = B_U + (size_t)S2_32 * 4; // 6*63 float
static constexpr size_t B_PAS   = B_PAC + 378 * 4;
static constexpr size_t B_PGC   = B_PAS + 378 * 4;
static constexpr size_t B_PGS   = B_PGC + 378 * 4;
static constexpr size_t B_WB    = B_PGS + 378 * 4;         // 128
static constexpr size_t B_WH    = B_WB + 128 * 4;          // 64
static constexpr size_t B_WQ    = B_WH + 64 * 4;           // 32
static constexpr size_t B_WINT  = B_WQ + 32 * 4;           // 32
static constexpr size_t BLOB_BYTES = B_WINT + 32 * 4;      // 191800

__host__ __device__ constexpr size_t AL(size_t x) { return (x + 255) & ~(size_t)255; }

// ---- workspace layout ----
static constexpr size_t O_TRIG  = AL(BLOB_BYTES);                       // 227*1024 float2
static constexpr size_t O_WS2   = AL(O_TRIG + (size_t)227 * 1024 * 8);  // [128][1024] f
static constexpr size_t O_WIGH  = AL(O_WS2 + (size_t)128 * 1024 * 4);   // [64][S2_32] f
static constexpr size_t O_WIG16 = AL(O_WIGH + (size_t)64 * S2_32 * 4);  // [64][S2_16]
static constexpr size_t O_WIGQ  = AL(O_WIG16 + (size_t)64 * S2_16 * 4); // [32][S2_16]
static constexpr size_t O_D3    = AL(O_WIGQ + (size_t)32 * S2_16 * 4);  // [S2_32]
static constexpr size_t O_D4    = AL(O_D3 + (size_t)S2_32 * 4);         // [S2_16]
static constexpr size_t O_D5    = AL(O_D4 + (size_t)S2_16 * 4);
static constexpr size_t O_FEAT  = AL(O_D5 + (size_t)S2_16 * 4);         // 128 f
static constexpr size_t O_A0    = AL(O_FEAT + 512);
static constexpr size_t SZ_BIG  = 68ull << 20;
static constexpr size_t SZ_MED  = 24ull << 20;
static constexpr size_t O_A1    = O_A0 + SZ_BIG;
static constexpr size_t O_A2    = O_A1 + SZ_BIG;
static constexpr size_t O_A3    = O_A2 + SZ_MED;
static constexpr size_t O_A4    = O_A3 + SZ_MED;
static constexpr size_t WS_REQ  = O_A4 + SZ_MED;   // ~224 MiB

// ---------------------------------------------------------------- host tables
struct HostTables { std::vector<unsigned char> blob; };

static void jacobi_sym(int n, std::vector<double>& A, std::vector<double>& V, std::vector<double>& w) {
  V.assign((size_t)n * n, 0.0);
  for (int i = 0; i < n; i++) V[(size_t)i * n + i] = 1.0;
  for (int sweep = 0; sweep < 80; ++sweep) {
    double off = 0;
    for (int p = 0; p < n; p++)
      for (int q = p + 1; q < n; q++) off += A[(size_t)p * n + q] * A[(size_t)p * n + q];
    if (off < 1e-26) break;
    for (int p = 0; p < n - 1; p++) {
      for (int q = p + 1; q < n; q++) {
        double apq = A[(size_t)p * n + q];
        if (fabs(apq) < 1e-300) continue;
        double app = A[(size_t)p * n + p], aqq = A[(size_t)q * n + q];
        double theta = (aqq - app) / (2.0 * apq);
        double t = ((theta >= 0) ? 1.0 : -1.0) / (fabs(theta) + sqrt(theta * theta + 1.0));
        double c = 1.0 / sqrt(t * t + 1.0), s = t * c;
        for (int i = 0; i < n; i++) {
          double aip = A[(size_t)i * n + p], aiq = A[(size_t)i * n + q];
          A[(size_t)i * n + p] = c * aip - s * aiq;
          A[(size_t)i * n + q] = s * aip + c * aiq;
        }
        for (int i = 0; i < n; i++) {
          double api = A[(size_t)p * n + i], aqi = A[(size_t)q * n + i];
          A[(size_t)p * n + i] = c * api - s * aqi;
          A[(size_t)q * n + i] = s * api + c * aqi;
        }
        for (int i = 0; i < n; i++) {
          double vip = V[(size_t)i * n + p], viq = V[(size_t)i * n + q];
          V[(size_t)i * n + p] = c * vip - s * viq;
          V[(size_t)i * n + q] = s * vip + c * viq;
        }
      }
    }
  }
  for (int i = 0; i < n; i++) w[i] = A[(size_t)i * n + i];
}

static HostTables build_tables() {
  HostTables ht;
  ht.blob.assign(BLOB_BYTES, 0);
  double* lam  = (double*)(ht.blob.data() + B_LAM);
  double* bet  = (double*)(ht.blob.data() + B_BETAS);
  float*  U    = (float*)(ht.blob.data() + B_U);
  float*  PAc  = (float*)(ht.blob.data() + B_PAC);
  float*  PAs  = (float*)(ht.blob.data() + B_PAS);
  float*  PGc  = (float*)(ht.blob.data() + B_PGC);
  float*  PGs  = (float*)(ht.blob.data() + B_PGS);
  float*  wbf  = (float*)(ht.blob.data() + B_WB);
  float*  whf  = (float*)(ht.blob.data() + B_WH);
  float*  wqf  = (float*)(ht.blob.data() + B_WQ);
  float*  wint = (float*)(ht.blob.data() + B_WINT);

  auto dh = [](int b, std::vector<double>& beta, std::vector<double>& w) {
    beta.resize(2 * b); w.resize(2 * b);
    for (int k = 0; k < 2 * b; k++) {
      double bk = M_PI * (2 * k + 1) / (4.0 * b);
      beta[k] = bk;
      double s = 0;
      for (int j = 0; j < b; j++) s += sin((2 * j + 1) * bk) / (2 * j + 1);
      w[k] = (2.0 / b) * sin(bk) * s;
    }
  };
  std::vector<double> bb, wb64, bh, wh32, bq, wq16;
  dh(64, bb, wb64); dh(32, bh, wh32); dh(16, bq, wq16);
  for (int k = 0; k < 128; k++) { bet[k] = bb[k]; wbf[k] = (float)wb64[k]; }
  for (int k = 0; k < 64; k++)  { bet[128 + k] = bh[k]; whf[k] = (float)wh32[k]; }
  for (int k = 0; k < 32; k++)  { bet[192 + k] = bq[k]; wqf[k] = (float)wq16[k]; }
  bet[224] = M_PI / 16.0; bet[225] = M_PI / 8.0; bet[226] = M_PI / 4.0;
  double sq = 0; for (int k = 0; k < 32; k++) sq += wq16[k];
  for (int k = 0; k < 32; k++) wint[k] = (float)(wq16[k] / (sq * 1024.0));

  // eigensystems: B real symm tridiag, zero diag, offdiag -c_j/2 (see D=diag(i^j) transform of exp(beta K))
  std::vector<double> A, V, w;
  for (int l = 0; l < 32; l++) {
    int n = 2 * l + 1;
    A.assign((size_t)n * n, 0.0);
    for (int j = 0; j < n - 1; j++) {
      double mj = -l + j;
      double c = sqrt((double)l * (l + 1) - mj * (mj + 1));
      A[(size_t)j * n + j + 1] = -c / 2.0;
      A[(size_t)(j + 1) * n + j] = -c / 2.0;
    }
    w.assign(n, 0.0);
    jacobi_sym(n, A, V, w);
    for (int r = 0; r < n; r++)
      for (int b2 = 0; b2 < n; b2++) U[off2c(l) + r * n + b2] = (float)V[(size_t)r * n + b2];
    for (int b2 = 0; b2 < n; b2++) lam[l * l + b2] = (double)llround(w[b2]); // Jy spectrum is exactly -l..l
  }
  for (int a = 0; a < 6; a++) {
    double al = 2.0 * M_PI * a / 6.0;
    for (int mi = 0; mi < 63; mi++) { int m = mi - 31; PAc[a * 63 + mi] = (float)cos(m * al); PAs[a * 63 + mi] = (float)sin(m * al); }
  }
  for (int c = 0; c < 6; c++) {
    double ga = -2.0 * M_PI + 4.0 * M_PI * c / 5.0;  // linspace(-2pi, 2pi, 6)
    for (int mi = 0; mi < 63; mi++) { int m = mi - 31; PGc[c * 63 + mi] = (float)cos(m * ga); PGs[c * 63 + mi] = (float)sin(m * ga); }
  }
  return ht;
}

// ---------------------------------------------------------------- device helpers
#define DEVFN static __device__ __forceinline__
DEVFN int isqrt_i(int p) {
  int l = (int)sqrtf((float)p);
  while (l * l > p) --l;
  while ((l + 1) * (l + 1) <= p) ++l;
  return l;
}

// ---------------------------------------------------------------- kernels
// trig tables: cos/sin(beta * lambda) for every (beta row, packed l*l+b)
__global__ void k_trig(const double* __restrict__ lam, const double* __restrict__ betas, float2* __restrict__ trig) {
  int id = blockIdx.x * blockDim.x + threadIdx.x;
  if (id >= 227 * 1024) return;
  int row = id >> 10, p = id & 1023;
  double a = betas[row] * lam[p];
  double s, c;
  sincos(a, &s, &c);
  trig[id] = make_float2((float)c, (float)s);
}

// W_s2[k][l*l+mi] = d^l_{m0}(beta_b[k]) * wb[k]
__global__ void k_ws2(const float* __restrict__ U, const float2* __restrict__ Tb, const float* __restrict__ wb, float* __restrict__ W) {
  int id = blockIdx.x * blockDim.x + threadIdx.x;
  if (id >= 128 * 1024) return;
  int k = id >> 10, p = id & 1023;
  int l = isqrt_i(p); int mi = p - l * l; int n = 2 * l + 1;
  const float* Ul = U + off2c(l);
  const float2* T = Tb + (size_t)k * 1024 + l * l;
  float ac = 0, as = 0;
  for (int b = 0; b < n; b++) { float uu = Ul[mi * n + b] * Ul[l * n + b]; ac += uu * T[b].x; as += uu * T[b].y; }
  int q = (mi - l) & 3;
  float v = (q & 1) ? as : ac; if (q & 2) v = -v;
  W[id] = v * wb[k];
}

// generic packed wigner-d build: out[k][off2(l)+r*(2l+1)+c] = d^l_{rc}(beta_k)
__global__ void k_wig(const float* __restrict__ U, const float2* __restrict__ trig, float* __restrict__ out, int S2L) {
  int l = blockIdx.y, k = blockIdx.z;
  int n = 2 * l + 1;
  int t = blockIdx.x * blockDim.x + threadIdx.x;
  if (t >= n * n) return;
  int r = t / n, c = t - r * n;
  const float* Ul = U + off2c(l);
  const float2* T = trig + (size_t)k * 1024 + l * l;
  float ac = 0, as = 0;
  for (int b = 0; b < n; b++) { float uu = Ul[r * n + b] * Ul[c * n + b]; ac += uu * T[b].x; as += uu * T[b].y; }
  int q = (r - c) & 3;
  float v = (q & 1) ? as : ac; if (q & 2) v = -v;
  out[(size_t)k * S2L + off2c(l) + t] = v;
}

// 1x1 conv + relu: h1[z,o,hw]
__global__ void k_conv1(const float* __restrict__ x, const float* __restrict__ w1, const float* __restrict__ b1, float* __restrict__ h1) {
  int id = blockIdx.x * blockDim.x + threadIdx.x;
  if (id >= 2 * 16 * 16384) return;
  int hw = id & 16383; int zo = id >> 14; int o = zo & 15; int z = zo >> 4;
  float acc = b1[o];
  for (int c = 0; c < 4; c++) acc += w1[o * 4 + c] * x[(size_t)(z * 4 + c) * 16384 + hw];
  h1[id] = fmaxf(acc, 0.f);
}

// alpha-DFT (layer2): xf[zi,k,j] = (1/128) sum_a h1[zi,k,a] e^{-2pi i (j-31) a/128}
__global__ void k_dft_a(const float* __restrict__ h1, float2* __restrict__ xf) {
  __shared__ float2 tw[128];
  int tid = threadIdx.x;
  if (tid < 128) { float ang = 6.28318530717958647692f * tid / 128.f; tw[tid] = make_float2(cosf(ang), -sinf(ang)); }
  __syncthreads();
  int id = blockIdx.x * blockDim.x + tid;
  if (id >= 2 * 16 * 128 * 63) return;
  int j = id % 63; int rest = id / 63; int k = rest & 127; int zi = rest >> 7;
  const float* row = h1 + ((size_t)zi * 128 + k) * 128;
  int mm = ((j - 31) + 128) & 127;
  float2 acc = make_float2(0.f, 0.f);
  int t = 0;
  for (int a = 0; a < 128; a++) {
    float2 w = tw[t];
    float hv = row[a];
    acc.x += hv * w.x; acc.y += hv * w.y;
    t += mm; t &= 127;
  }
  xf[id] = make_float2(acc.x / 128.f, acc.y / 128.f);
}

// X2[zi][l*l+mi] = sum_k Ws2[k][p] * xf2[zi,k,jm]
__global__ void k_x2(const float* __restrict__ W, const float2* __restrict__ xf, float2* __restrict__ X) {
  int id = blockIdx.x * blockDim.x + threadIdx.x;
  if (id >= 2 * 16 * 1024) return;
  int p = id & 1023; int zi = id >> 10;
  int l = isqrt_i(p); int mi = p - l * l; int jm = mi - l + 31;
  float2 acc = make_float2(0.f, 0.f);
  for (int k = 0; k < 128; k++) {
    float w = W[(size_t)k * 1024 + p];
    float2 v = xf[((size_t)zi * 128 + k) * 63 + jm];
    acc.x += w * v.x; acc.y += w * v.y;
  }
  X[id] = acc;
}

// kappa2[i*16+o][j] = sum_a k2[i,o,a] e^{i (j-31) alpha_a}
__global__ void k_kap2(const float* __restrict__ k2, const float* __restrict__ PAc, const float* __restrict__ PAs, float2* __restrict__ kap) {
  int id = blockIdx.x * blockDim.x + threadIdx.x;
  if (id >= 16 * 16 * 63) return;
  int j = id % 63; int io = id / 63;
  float2 acc = make_float2(0.f, 0.f);
  for (int a = 0; a < 6; a++) {
    float kv = k2[io * 6 + a];
    acc.x += kv * PAc[a * 63 + j]; acc.y += kv * PAs[a * 63 + j];
  }
  kap[id] = acc;
}

// Y2[z,o,pk] = sum_i X2[z,i,l*l+mi] * conj(d^l_{n0} kappa2[i,o,jn])
__global__ void k_y2(const float2* __restrict__ X, const float2* __restrict__ kap, const float* __restrict__ d3, float2* __restrict__ Y) {
  int l = blockIdx.y; int n21 = 2 * l + 1;
  int t = blockIdx.x * blockDim.x + threadIdx.x;
  if (t >= n21 * n21) return;
  int zo = blockIdx.z; int o = zo & 15; int z = zo >> 4;
  int mi = t / n21, ni = t - mi * n21;
  float dv = d3[off2c(l) + ni * n21 + l];
  int jn = ni - l + 31;
  float2 acc = make_float2(0.f, 0.f);
  for (int i = 0; i < 16; i++) {
    float2 xv = X[(size_t)(z * 16 + i) * 1024 + l * l + mi];
    float2 kv = kap[(size_t)(i * 16 + o) * 63 + jn];
    acc.x += dv * (xv.x * kv.x + xv.y * kv.y);
    acc.y += dv * (xv.y * kv.x - xv.x * kv.y);
  }
  Y[(size_t)(z * 16 + o) * S2_32 + off2c(l) + t] = acc;
}

// ---------------------------------------------------------------- k_y as fused complex GEMM (v1 — verified, 0 bank conflicts)
// Y[z,o,l,mi,ni] = sum_{i,p} X[z,i,l,mi,p] * (d^l[ni,p] * conj(kap[i,o,jn,jp]))
// GEMM per (z,l): M=n21 (mi), N=CO*n21 (o,ni), K=CI*n21 (i,p); B built on the fly.
template <int CI, int CO, int L>
__global__ __launch_bounds__(256) void k_y_gemm(const float2* __restrict__ X, const float2* __restrict__ kap,
                                                const float* __restrict__ dtab, float2* __restrict__ Y, int S2L) {
  constexpr int NF = 2 * L - 1;
  constexpr int BM = 32, BN = 64, BK = 32;
  const int l = blockIdx.y;
  const int n21 = 2 * l + 1;
  const int Kdim = CI * n21;
  const int N = CO * n21;
  const int ntn = (N + BN - 1) / BN;
  const int ntm = (n21 + BM - 1) / BM;
  if ((int)blockIdx.x >= ntm * ntn) return;
  const int tm = blockIdx.x / ntn, tn = blockIdx.x % ntn;
  const int z = blockIdx.z;
  const int off = off2c(l);
  const float2* Xz = X + (size_t)z * CI * S2L + off;
  float2* Yz = Y + (size_t)z * CO * S2L + off;
  const float* dl = dtab + off;

  __shared__ float2 As[BM][BK + 1];
  __shared__ float2 Bs[BK][BN + 1];
  __shared__ int nLUT_o[BN];
  __shared__ short nLUT_ni[BN];

  const int tid = threadIdx.x;
  if (tid < BN) {
    int ng = tn * BN + tid;
    int o = ng / n21;
    nLUT_o[tid] = (ng < N) ? o : -1;
    nLUT_ni[tid] = (short)(ng - o * n21);
  }
  const int kk = tid & 31;   // load lane: K index within tile (fixed per thread)
  const int rr = tid >> 5;   // 0..7
  const int mrow = tid >> 4; // 0..15 compute row base
  const int ncol = tid & 15; // compute col base
  float2 acc[2][4];
  #pragma unroll
  for (int a = 0; a < 2; a++)
    #pragma unroll
    for (int b = 0; b < 4; b++) acc[a][b] = make_float2(0.f, 0.f);
  __syncthreads();

  for (int k0 = 0; k0 < Kdim; k0 += BK) {
    int kg = k0 + kk;
    int i = (unsigned)kg / (unsigned)n21;
    int p = kg - i * n21;
    bool kok = kg < Kdim;
    // A fill: As[m][kk] = X[z,i,mi,p]
    #pragma unroll
    for (int s = 0; s < 4; s++) {
      int m = rr + s * 8;
      int mg = tm * BM + m;
      float2 v = make_float2(0.f, 0.f);
      if (kok && mg < n21) v = Xz[(size_t)i * S2L + mg * n21 + p];
      As[m][kk] = v;
    }
    // B fill: Bs[kk][nn] = d[ni,p] * conj(kap[i,o,jn,jp])
    int jp = p - l + (L - 1);
    #pragma unroll
    for (int s = 0; s < 8; s++) {
      int nn = rr + s * 8;
      float2 v = make_float2(0.f, 0.f);
      int o = nLUT_o[nn];
      if (kok && o >= 0) {
        int ni = nLUT_ni[nn];
        float dv = dl[ni * n21 + p];
        int jn = ni - l + (L - 1);
        float2 kv = kap[(size_t)(i * CO + o) * NF * NF + jn * NF + jp];
        v = make_float2(dv * kv.x, -dv * kv.y);
      }
      Bs[kk][nn] = v;
    }
    __syncthreads();
    #pragma unroll
    for (int q = 0; q < BK; q++) {
      float2 a0 = As[mrow][q];
      float2 a1 = As[mrow + 16][q];
      #pragma unroll
      for (int j = 0; j < 4; j++) {
        float2 b = Bs[q][ncol + j * 16];
        acc[0][j].x += a0.x * b.x - a0.y * b.y;
        acc[0][j].y += a0.x * b.y + a0.y * b.x;
        acc[1][j].x += a1.x * b.x - a1.y * b.y;
        acc[1][j].y += a1.x * b.y + a1.y * b.x;
      }
    }
    __syncthreads();
  }
  #pragma unroll
  for (int sm = 0; sm < 2; sm++) {
    int mg = tm * BM + mrow + sm * 16;
    if (mg >= n21) continue;
    #pragma unroll
    for (int j = 0; j < 4; j++) {
      int nn = ncol + j * 16;
      int o = nLUT_o[nn];
      if (o < 0) continue;
      int ni = nLUT_ni[nn];
      Yz[(size_t)o * S2L + mg * n21 + ni] = acc[sm][j];
    }
  }
}

// F[zc,k,jm,jn] = sum_l (2l+1) * wig[k][pk] * Y[zc][pk]  (dense in (jm,jn))
// v2: each thread computes TWO adjacent jn outputs — independent load chains (2x MLP),
// pk and pk+1 share cache lines in both wig and Y.
__global__ void k_f(const float* __restrict__ wig, const float2* __restrict__ Y, float2* __restrict__ F,
                    int nzc, int NK, int L, int S2L) {
  int NF = 2 * L - 1;
  int NH = (NF + 1) / 2;
  size_t id = (size_t)blockIdx.x * blockDim.x + threadIdx.x;
  size_t tot = (size_t)nzc * NK * NF * NH;
  if (id >= tot) return;
  int jh = (int)(id % NH); size_t r1 = id / NH;
  int jm = (int)(r1 % NF); size_t r2 = r1 / NF;
  int k = (int)(r2 % NK); int zc = (int)(r2 / NK);
  int jn0 = 2 * jh;
  bool two = (jn0 + 1 < NF);
  int m = jm - (L - 1);
  int n0 = jn0 - (L - 1), n1 = n0 + 1;
  int am = m < 0 ? -m : m;
  int an0 = n0 < 0 ? -n0 : n0, an1 = n1 < 0 ? -n1 : n1;
  int lmin0 = am > an0 ? am : an0;
  int lmin1 = am > an1 ? am : an1;
  int lmin = lmin0 < lmin1 ? lmin0 : lmin1;
  float2 acc0 = make_float2(0.f, 0.f), acc1 = make_float2(0.f, 0.f);
  const float* wk = wig + (size_t)k * S2L;
  const float2* Yc = Y + (size_t)zc * S2L;
  for (int l = lmin; l < L; l++) {
    int n21 = 2 * l + 1;
    int base = off2c(l) + (m + l) * n21 + l;   // + n gives pk
    if (l >= lmin0) {
      int pk = base + n0;
      float w = wk[pk] * (float)n21;
      float2 yv = Yc[pk];
      acc0.x += w * yv.x; acc0.y += w * yv.y;
    }
    if (two && l >= lmin1) {
      int pk = base + n1;
      float w = wk[pk] * (float)n21;
      float2 yv = Yc[pk];
      acc1.x += w * yv.x; acc1.y += w * yv.y;
    }
  }
  size_t ob = (((size_t)zc * NK + k) * NF + jm) * NF + jn0;
  F[ob] = acc0;
  if (two) F[ob + 1] = acc1;
}

// fused 2-stage inverse DFT  F[zc,k,:,:] -> h[zc,k,u,v] (+bias, relu)
template <int L, int B2>
__global__ void k_synth(const float2* __restrict__ F, const float* __restrict__ bias, float* __restrict__ h, int C, int NK) {
  constexpr int NF = 2 * L - 1;
  __shared__ float2 Ft[NF * NF];
  __shared__ float2 Gt[NF * B2];
  __shared__ float2 tw[B2];
  int bid = blockIdx.x;         // zc*NK + k
  int zc = bid / NK;
  int c = zc % C;
  int tid = threadIdx.x, nt = blockDim.x;
  for (int t = tid; t < B2; t += nt) { float ang = 6.28318530717958647692f * t / B2; tw[t] = make_float2(cosf(ang), sinf(ang)); }
  const float2* Fb = F + (size_t)bid * NF * NF;
  for (int idx = tid; idx < NF * NF; idx += nt) Ft[idx] = Fb[idx];
  __syncthreads();
  for (int idx = tid; idx < NF * B2; idx += nt) {
    int jm = idx / B2, v = idx - jm * B2;
    float2 acc = make_float2(0.f, 0.f);
    int t = ((-(L - 1) * v) % B2 + B2) % B2;
    for (int jn = 0; jn < NF; jn++) {
      float2 fv = Ft[jm * NF + jn];
      float2 w = tw[t];
      acc.x += fv.x * w.x - fv.y * w.y;
      acc.y += fv.x * w.y + fv.y * w.x;
      t += v; if (t >= B2) t -= B2;
    }
    Gt[idx] = acc;
  }
  __syncthreads();
  float bv = bias[c];
  float* hb = h + (size_t)bid * B2 * B2;
  for (int idx = tid; idx < B2 * B2; idx += nt) {
    int u = idx / B2, v = idx - u * B2;
    float acc = 0;
    int t = ((-(L - 1) * u) % B2 + B2) % B2;
    for (int jm = 0; jm < NF; jm++) {
      float2 gv = Gt[jm * B2 + v];
      float2 w = tw[t];
      acc += gv.x * w.x - gv.y * w.y;
      t += u; if (t >= B2) t -= B2;
    }
    hb[idx] = fmaxf(acc + bv, 0.f);
  }
}

// fused 2-stage forward DFT: h[zc,k,:,:] -> xf[zc,k,jm,jn] (truncated, /B2^2)
template <int L, int B2>
__global__ void k_fwd(const float* __restrict__ h, float2* __restrict__ xf) {
  constexpr int NF = 2 * L - 1;
  __shared__ float ht[B2 * B2];
  __shared__ float2 Tt[B2 * NF];
  __shared__ float2 tw[B2];
  int bid = blockIdx.x;
  int tid = threadIdx.x, nt = blockDim.x;
  for (int t = tid; t < B2; t += nt) { float ang = 6.28318530717958647692f * t / B2; tw[t] = make_float2(cosf(ang), -sinf(ang)); }
  const float* hb = h + (size_t)bid * B2 * B2;
  for (int idx = tid; idx < B2 * B2; idx += nt) ht[idx] = hb[idx];
  __syncthreads();
  for (int idx = tid; idx < B2 * NF; idx += nt) {
    int u = idx / NF, jn = idx - u * NF;
    int mm = ((jn - (L - 1)) % B2 + B2) % B2;
    float2 acc = make_float2(0.f, 0.f);
    int t = 0;
    for (int v = 0; v < B2; v++) {
      float hv = ht[u * B2 + v];
      float2 w = tw[t];
      acc.x += hv * w.x; acc.y += hv * w.y;
      t += mm; if (t >= B2) t -= B2;
    }
    Tt[idx] = acc;
  }
  __syncthreads();
  float2* xb = xf + (size_t)bid * NF * NF;
  const float inv = 1.f / ((float)B2 * (float)B2);
  for (int idx = tid; idx < NF * NF; idx += nt) {
    int jm = idx / NF, jn = idx - jm * NF;
    int mm = ((jm - (L - 1)) % B2 + B2) % B2;
    float2 acc = make_float2(0.f, 0.f);
    int t = 0;
    for (int u = 0; u < B2; u++) {
      float2 tv = Tt[u * NF + jn];
      float2 w = tw[t];
      acc.x += tv.x * w.x - tv.y * w.y;
      acc.y += tv.x * w.y + tv.y * w.x;
      t += mm; if (t >= B2) t -= B2;
    }
    xb[idx] = make_float2(acc.x * inv, acc.y * inv);
  }
}

// X[zi][pk] = sum_k wgt[k] * wig[k][pk] * xf[zi,k,jm,jn]
__global__ void k_xc(const float* __restrict__ wig, const float* __restrict__ wgt, const float2* __restrict__ xf,
                     float2* __restrict__ X, int NK, int L, int S2L) {
  int NF = 2 * L - 1;
  int l = blockIdx.y; int n21 = 2 * l + 1;
  int t = blockIdx.x * blockDim.x + threadIdx.x;
  if (t >= n21 * n21) return;
  int zi = blockIdx.z;
  int mi = t / n21, ni = t - mi * n21;
  int jm = mi - l + (L - 1), jn = ni - l + (L - 1);
  int pk = off2c(l) + t;
  float2 acc = make_float2(0.f, 0.f);
  for (int k = 0; k < NK; k++) {
    float w = wig[(size_t)k * S2L + pk] * wgt[k];
    float2 v = xf[((size_t)zi * NK + k) * NF * NF + jm * NF + jn];
    acc.x += w * v.x; acc.y += w * v.y;
  }
  X[(size_t)zi * S2L + pk] = acc;
}

// kappa[io][jn][jp] = sum_{a,c} ker[io,a*6+c] e^{i m_n alpha_a} e^{i m_p gamma_c}
__global__ void k_kap(const float* __restrict__ ker, const float* __restrict__ PAc, const float* __restrict__ PAs,
                      const float* __restrict__ PGc, const float* __restrict__ PGs,
                      float2* __restrict__ kap, int NIO, int NF, int poff) {
  int id = blockIdx.x * blockDim.x + threadIdx.x;
  if (id >= NIO * NF * NF) return;
  int jp = id % NF; int r = id / NF; int jn = r % NF; int io = r / NF;
  float2 acc = make_float2(0.f, 0.f);
  for (int a = 0; a < 6; a++) {
    float pac = PAc[a * 63 + jn + poff], pas = PAs[a * 63 + jn + poff];
    for (int c = 0; c < 6; c++) {
      float kv = ker[io * 36 + a * 6 + c];
      float pgc = PGc[c * 63 + jp + poff], pgs = PGs[c * 63 + jp + poff];
      acc.x += kv * (pac * pgc - pas * pgs);
      acc.y += kv * (pac * pgs + pas * pgc);
    }
  }
  kap[id] = acc;
}

// feat[zc] = sum_{beta,u,v} h5[zc,beta,u,v] * wint[beta]
__global__ void k_feat(const float* __restrict__ h5, const float* __restrict__ wint, float* __restrict__ feat) {
  __shared__ float red[256];
  int zc = blockIdx.x;
  const float* hb = h5 + (size_t)zc * 32768;
  float acc = 0;
  for (int idx = threadIdx.x; idx < 32768; idx += 256) acc += hb[idx] * wint[idx >> 10];
  red[threadIdx.x] = acc;
  __syncthreads();
  for (int s = 128; s > 0; s >>= 1) { if (threadIdx.x < s) red[threadIdx.x] += red[threadIdx.x + s]; __syncthreads(); }
  if (threadIdx.x == 0) feat[zc] = red[0];
}

// MLP head per batch row
__global__ void k_head(const float* __restrict__ feat, const float* __restrict__ m, const float* __restrict__ wm,
                       const float* __restrict__ bm, const float* __restrict__ wl1, const float* __restrict__ bl1,
                       const float* __restrict__ wl2, const float* __restrict__ bl2, float* __restrict__ out) {
  __shared__ float zin[68];
  __shared__ float red[512];
  int z = blockIdx.x, tid = threadIdx.x;
  if (tid < 64) zin[tid] = feat[z * 64 + tid];
  else if (tid < 68) zin[tid] = fmaxf(m[z] * wm[tid - 64] + bm[tid - 64], 0.f);
  __syncthreads();
  float part = 0;
  for (int q = tid; q < 500; q += 512) {
    float acc = bl1[q];
    for (int j = 0; j < 68; j++) acc += zin[j] * wl1[q * 68 + j];
    part += fmaxf(acc, 0.f) * wl2[q];
  }
  red[tid] = part;
  __syncthreads();
  for (int s = 256; s > 0; s >>= 1) { if (tid < s) red[tid] += red[tid + s]; __syncthreads(); }
  if (tid == 0) out[z] = red[0] + bl2[0];
}

// ---------------------------------------------------------------- launch
extern "C" void kernel_launch(void* const* d_in, const int* in_sizes, int n_in,
                              void* d_out, int out_size, void* d_ws, size_t ws_size,
                              hipStream_t stream) {
  static HostTables HT = build_tables();  // host-only, once

  if (ws_size < WS_REQ) {
    fprintf(stderr, "[s2cnn] ws too small: need %zu bytes, got %zu\n", (size_t)WS_REQ, ws_size);
    return;
  }
  if (n_in < 18) { fprintf(stderr, "[s2cnn] bad n_in %d\n", n_in); return; }

  const float* x   = (const float*)d_in[0];
  const float* mI  = (const float*)d_in[1];
  const float* w1  = (const float*)d_in[2];
  const float* b1  = (const float*)d_in[3];
  const float* k2  = (const float*)d_in[4];
  const float* bb2 = (const float*)d_in[5];
  const float* k3  = (const float*)d_in[6];
  const float* bb3 = (const float*)d_in[7];
  const float* k4  = (const float*)d_in[8];
  const float* bb4 = (const float*)d_in[9];
  const float* k5  = (const float*)d_in[10];
  const float* bb5 = (const float*)d_in[11];
  const float* wm  = (const float*)d_in[12];
  const float* bm  = (const float*)d_in[13];
  const float* wl1 = (const float*)d_in[14];
  const float* bl1 = (const float*)d_in[15];
  const float* wl2 = (const float*)d_in[16];
  const float* bl2 = (const float*)d_in[17];
  float* out = (float*)d_out;

  char* ws = (char*)d_ws;
  // upload constant blob (192 KB)
  hipMemcpyAsync(ws, HT.blob.data(), BLOB_BYTES, hipMemcpyHostToDevice, stream);

  const double* dLam  = (const double*)(ws + B_LAM);
  const double* dBet  = (const double*)(ws + B_BETAS);
  const float*  dU    = (const float*)(ws + B_U);
  const float*  dPAc  = (const float*)(ws + B_PAC);
  const float*  dPAs  = (const float*)(ws + B_PAS);
  const float*  dPGc  = (const float*)(ws + B_PGC);
  const float*  dPGs  = (const float*)(ws + B_PGS);
  const float*  dWb   = (const float*)(ws + B_WB);
  const float*  dWh   = (const float*)(ws + B_WH);
  const float*  dWq   = (const float*)(ws + B_WQ);
  const float*  dWint = (const float*)(ws + B_WINT);

  float2* TRIG = (float2*)(ws + O_TRIG);
  float2* Tb = TRIG;                 // 128 rows
  float2* Th = TRIG + (size_t)128 * 1024;
  float2* Tq = TRIG + (size_t)192 * 1024;
  float2* Ts16 = TRIG + (size_t)224 * 1024;
  float2* Ts8  = TRIG + (size_t)225 * 1024;
  float2* Ts4  = TRIG + (size_t)226 * 1024;
  float* WS2   = (float*)(ws + O_WS2);
  float* WIGH  = (float*)(ws + O_WIGH);
  float* WIG16 = (float*)(ws + O_WIG16);
  float* WIGQ  = (float*)(ws + O_WIGQ);
  float* D3    = (float*)(ws + O_D3);
  float* D4    = (float*)(ws + O_D4);
  float* D5    = (float*)(ws + O_D5);
  float* FEAT  = (float*)(ws + O_FEAT);
  char* A0 = ws + O_A0;
  char* A1 = ws + O_A1;
  char* A2 = ws + O_A2;
  char* A3 = ws + O_A3;
  char* A4 = ws + O_A4;

  // ---- build tables on device (cheap, every call: ws is re-poisoned)
  k_trig<<<(227 * 1024 + 255) / 256, 256, 0, stream>>>(dLam, dBet, TRIG);
  k_ws2<<<(128 * 1024 + 255) / 256, 256, 0, stream>>>(dU, Tb, dWb, WS2);
  k_wig<<<dim3(16, 32, 64), 256, 0, stream>>>(dU, Th, WIGH, S2_32);
  k_wig<<<dim3(4, 16, 64), 256, 0, stream>>>(dU, Th, WIG16, S2_16);
  k_wig<<<dim3(4, 16, 32), 256, 0, stream>>>(dU, Tq, WIGQ, S2_16);
  k_wig<<<dim3(16, 32, 1), 256, 0, stream>>>(dU, Ts16, D3, S2_32);
  k_wig<<<dim3(4, 16, 1), 256, 0, stream>>>(dU, Ts8, D4, S2_16);
  k_wig<<<dim3(4, 16, 1), 256, 0, stream>>>(dU, Ts4, D5, S2_16);

  // ---- layer 1: 1x1 conv + relu -> h1 (A2)
  float* h1 = (float*)A2;
  k_conv1<<<(2 * 16 * 16384 + 255) / 256, 256, 0, stream>>>(x, w1, b1, h1);

  // ---- layer 2: s2 conv
  float2* xf2 = (float2*)A0;
  k_dft_a<<<(2 * 16 * 128 * 63 + 255) / 256, 256, 0, stream>>>(h1, xf2);
  float2* X2 = (float2*)A3;
  k_x2<<<(2 * 16 * 1024 + 255) / 256, 256, 0, stream>>>(WS2, xf2, X2);
  float2* kap2 = (float2*)A4;
  k_kap2<<<(16 * 16 * 63 + 255) / 256, 256, 0, stream>>>(k2, dPAc, dPAs, kap2);
  float2* Y2 = (float2*)A1;
  k_y2<<<dim3(16, 32, 32), 256, 0, stream>>>(X2, kap2, D3, Y2);
  float2* F2 = (float2*)A0;
  k_f<<<(2 * 16 * 64 * 63 * 32 + 255) / 256, 256, 0, stream>>>(WIGH, Y2, F2, 32, 64, 32, S2_32);
  float* h2 = (float*)A1;
  k_synth<32, 64><<<2 * 16 * 64, 256, 0, stream>>>(F2, bb2, h2, 16, 64);

  // ---- layer 3: so3 conv (b=32, L=32)
  float2* xf3 = (float2*)A0;
  k_fwd<32, 64><<<2 * 16 * 64, 256, 0, stream>>>(h2, xf3);
  float2* X3 = (float2*)A2;
  k_xc<<<dim3(16, 32, 2 * 16), 256, 0, stream>>>(WIGH, dWh, xf3, X3, 64, 32, S2_32);
  float2* kap3 = (float2*)A3;
  k_kap<<<(16 * 32 * 63 * 63 + 255) / 256, 256, 0, stream>>>(k3, dPAc, dPAs, dPGc, dPGs, kap3, 16 * 32, 63, 0);
  float2* Y3 = (float2*)A4;
  k_y_gemm<16, 32, 32><<<dim3(64, 32, 2), 256, 0, stream>>>(X3, kap3, D3, Y3, S2_32);
  float* h3 = (float*)A1;
  for (int z = 0; z < 2; z++) {
    float2* F3 = (float2*)A0;
    k_f<<<(32 * 64 * 63 * 32 + 255) / 256, 256, 0, stream>>>(WIGH, Y3 + (size_t)z * 32 * S2_32, F3, 32, 64, 32, S2_32);
    k_synth<32, 64><<<32 * 64, 256, 0, stream>>>(F3, bb3, h3 + (size_t)z * 32 * 64 * 4096, 32, 64);
  }

  // ---- layer 4: so3 conv (b=32 -> 16, L=16)
  float2* xf4 = (float2*)A0;
  k_fwd<16, 64><<<2 * 32 * 64, 256, 0, stream>>>(h3, xf4);
  float2* X4 = (float2*)A2;
  k_xc<<<dim3(4, 16, 2 * 32), 256, 0, stream>>>(WIG16, dWh, xf4, X4, 64, 16, S2_16);
  float2* kap4 = (float2*)A3;
  k_kap<<<(32 * 32 * 31 * 31 + 255) / 256, 256, 0, stream>>>(k4, dPAc, dPAs, dPGc, dPGs, kap4, 32 * 32, 31, 16);
  float2* Y4 = (float2*)A4;
  k_y_gemm<32, 32, 16><<<dim3(16, 16, 2), 256, 0, stream>>>(X4, kap4, D4, Y4, S2_16);
  float2* F4 = (float2*)A1;
  k_f<<<(2 * 32 * 32 * 31 * 16 + 255) / 256, 256, 0, stream>>>(WIGQ, Y4, F4, 64, 32, 16, S2_16);
  float* h4 = (float*)A0;
  k_synth<16, 32><<<2 * 32 * 32, 256, 0, stream>>>(F4, bb4, h4, 32, 32);

  // ---- layer 5: so3 conv (b=16, L=16)
  float2* xf5 = (float2*)A1;
  k_fwd<16, 32><<<2 * 32 * 32, 256, 0, stream>>>(h4, xf5);
  float2* X5 = (float2*)A2;
  k_xc<<<dim3(4, 16, 2 * 32), 256, 0, stream>>>(WIGQ, dWq, xf5, X5, 32, 16, S2_16);
  float2* kap5 = (float2*)A3;
  k_kap<<<(32 * 64 * 31 * 31 + 255) / 256, 256, 0, stream>>>(k5, dPAc, dPAs, dPGc, dPGs, kap5, 32 * 64, 31, 16);
  float2* Y5 = (float2*)A4;
  k_y_gemm<32, 64, 16><<<dim3(31, 16, 2), 256, 0, stream>>>(X5, kap5, D5, Y5, S2_16);
  float2* F5 = (float2*)A0;
  k_f<<<(2 * 64 * 32 * 31 * 16 + 255) / 256, 256, 0, stream>>>(WIGQ, Y5, F5, 128, 32, 16, S2_16);
  float* h5 = (float*)A1;
  k_synth<16, 32><<<2 * 64 * 32, 256, 0, stream>>>(F5, bb5, h5, 64, 32);

  // ---- head
  k_feat<<<128, 256, 0, stream>>>(h5, dWint, FEAT);
  k_head<<<2, 512, 0, stream>>>(FEAT, mI, wm, bm, wl1, bl1, wl2, bl2, out);
}

// Round 11
// 4409.946 us; speedup vs baseline: 2.1894x; 1.2119x over previous
//
#include <hip/hip_runtime.h>
#include <cstdio>
#include <cmath>
#include <cstring>
#include <vector>

#ifndef M_PI
#define M_PI 3.14159265358979323846
#endif

// ---------------------------------------------------------------- constants
__host__ __device__ constexpr int off2c(int l) { return l * (2 * l - 1) * (2 * l + 1) / 3; }

static constexpr int S2_32 = off2c(32);   // 43680 = sum (2l+1)^2, l<32
static constexpr int S2_16 = off2c(16);   // 5456

// ---- host blob layout (bytes) ----
static constexpr size_t B_LAM   = 0;                       // 1024 double (eigenvalues, packed l*l+b)
static constexpr size_t B_BETAS = 1024 * 8;                // 227 double
static constexpr size_t B_U     = B_BETAS + 227 * 8;       // 43680 float (packed eigvec mats)
static constexpr size_t B_PAC   = B_U + (size_t)S2_32 * 4; // 6*63 float
static constexpr size_t B_PAS   = B_PAC + 378 * 4;
static constexpr size_t B_PGC   = B_PAS + 378 * 4;
static constexpr size_t B_PGS   = B_PGC + 378 * 4;
static constexpr size_t B_WB    = B_PGS + 378 * 4;         // 128
static constexpr size_t B_WH    = B_WB + 128 * 4;          // 64
static constexpr size_t B_WQ    = B_WH + 64 * 4;           // 32
static constexpr size_t B_WINT  = B_WQ + 32 * 4;           // 32
static constexpr size_t BLOB_BYTES = B_WINT + 32 * 4;      // 191800

__host__ __device__ constexpr size_t AL(size_t x) { return (x + 255) & ~(size_t)255; }

// ---- workspace layout ----
static constexpr size_t O_TRIG  = AL(BLOB_BYTES);                       // 227*1024 float2
static constexpr size_t O_WS2   = AL(O_TRIG + (size_t)227 * 1024 * 8);  // [128][1024] f
static constexpr size_t O_WIGH  = AL(O_WS2 + (size_t)128 * 1024 * 4);   // [64][S2_32] f
static constexpr size_t O_WIG16 = AL(O_WIGH + (size_t)64 * S2_32 * 4);  // [64][S2_16]
static constexpr size_t O_WIGQ  = AL(O_WIG16 + (size_t)64 * S2_16 * 4); // [32][S2_16]
static constexpr size_t O_D3    = AL(O_WIGQ + (size_t)32 * S2_16 * 4);  // [S2_32]
static constexpr size_t O_D4    = AL(O_D3 + (size_t)S2_32 * 4);         // [S2_16]
static constexpr size_t O_D5    = AL(O_D4 + (size_t)S2_16 * 4);
static constexpr size_t O_FEAT  = AL(O_D5 + (size_t)S2_16 * 4);         // 128 f
static constexpr size_t O_A0    = AL(O_FEAT + 512);
static constexpr size_t SZ_BIG  = 68ull << 20;
static constexpr size_t SZ_MED  = 24ull << 20;
static constexpr size_t O_A1    = O_A0 + SZ_BIG;
static constexpr size_t O_A2    = O_A1 + SZ_BIG;
static constexpr size_t O_A3    = O_A2 + SZ_MED;
static constexpr size_t O_A4    = O_A3 + SZ_MED;
static constexpr size_t WS_REQ  = O_A4 + SZ_MED;   // ~224 MiB

// ---------------------------------------------------------------- host tables
struct HostTables { std::vector<unsigned char> blob; };

static void jacobi_sym(int n, std::vector<double>& A, std::vector<double>& V, std::vector<double>& w) {
  V.assign((size_t)n * n, 0.0);
  for (int i = 0; i < n; i++) V[(size_t)i * n + i] = 1.0;
  for (int sweep = 0; sweep < 80; ++sweep) {
    double off = 0;
    for (int p = 0; p < n; p++)
      for (int q = p + 1; q < n; q++) off += A[(size_t)p * n + q] * A[(size_t)p * n + q];
    if (off < 1e-26) break;
    for (int p = 0; p < n - 1; p++) {
      for (int q = p + 1; q < n; q++) {
        double apq = A[(size_t)p * n + q];
        if (fabs(apq) < 1e-300) continue;
        double app = A[(size_t)p * n + p], aqq = A[(size_t)q * n + q];
        double theta = (aqq - app) / (2.0 * apq);
        double t = ((theta >= 0) ? 1.0 : -1.0) / (fabs(theta) + sqrt(theta * theta + 1.0));
        double c = 1.0 / sqrt(t * t + 1.0), s = t * c;
        for (int i = 0; i < n; i++) {
          double aip = A[(size_t)i * n + p], aiq = A[(size_t)i * n + q];
          A[(size_t)i * n + p] = c * aip - s * aiq;
          A[(size_t)i * n + q] = s * aip + c * aiq;
        }
        for (int i = 0; i < n; i++) {
          double api = A[(size_t)p * n + i], aqi = A[(size_t)q * n + i];
          A[(size_t)p * n + i] = c * api - s * aqi;
          A[(size_t)q * n + i] = s * api + c * aqi;
        }
        for (int i = 0; i < n; i++) {
          double vip = V[(size_t)i * n + p], viq = V[(size_t)i * n + q];
          V[(size_t)i * n + p] = c * vip - s * viq;
          V[(size_t)i * n + q] = s * vip + c * viq;
        }
      }
    }
  }
  for (int i = 0; i < n; i++) w[i] = A[(size_t)i * n + i];
}

static HostTables build_tables() {
  HostTables ht;
  ht.blob.assign(BLOB_BYTES, 0);
  double* lam  = (double*)(ht.blob.data() + B_LAM);
  double* bet  = (double*)(ht.blob.data() + B_BETAS);
  float*  U    = (float*)(ht.blob.data() + B_U);
  float*  PAc  = (float*)(ht.blob.data() + B_PAC);
  float*  PAs  = (float*)(ht.blob.data() + B_PAS);
  float*  PGc  = (float*)(ht.blob.data() + B_PGC);
  float*  PGs  = (float*)(ht.blob.data() + B_PGS);
  float*  wbf  = (float*)(ht.blob.data() + B_WB);
  float*  whf  = (float*)(ht.blob.data() + B_WH);
  float*  wqf  = (float*)(ht.blob.data() + B_WQ);
  float*  wint = (float*)(ht.blob.data() + B_WINT);

  auto dh = [](int b, std::vector<double>& beta, std::vector<double>& w) {
    beta.resize(2 * b); w.resize(2 * b);
    for (int k = 0; k < 2 * b; k++) {
      double bk = M_PI * (2 * k + 1) / (4.0 * b);
      beta[k] = bk;
      double s = 0;
      for (int j = 0; j < b; j++) s += sin((2 * j + 1) * bk) / (2 * j + 1);
      w[k] = (2.0 / b) * sin(bk) * s;
    }
  };
  std::vector<double> bb, wb64, bh, wh32, bq, wq16;
  dh(64, bb, wb64); dh(32, bh, wh32); dh(16, bq, wq16);
  for (int k = 0; k < 128; k++) { bet[k] = bb[k]; wbf[k] = (float)wb64[k]; }
  for (int k = 0; k < 64; k++)  { bet[128 + k] = bh[k]; whf[k] = (float)wh32[k]; }
  for (int k = 0; k < 32; k++)  { bet[192 + k] = bq[k]; wqf[k] = (float)wq16[k]; }
  bet[224] = M_PI / 16.0; bet[225] = M_PI / 8.0; bet[226] = M_PI / 4.0;
  double sq = 0; for (int k = 0; k < 32; k++) sq += wq16[k];
  for (int k = 0; k < 32; k++) wint[k] = (float)(wq16[k] / (sq * 1024.0));

  // eigensystems: B real symm tridiag, zero diag, offdiag -c_j/2 (see D=diag(i^j) transform of exp(beta K))
  std::vector<double> A, V, w;
  for (int l = 0; l < 32; l++) {
    int n = 2 * l + 1;
    A.assign((size_t)n * n, 0.0);
    for (int j = 0; j < n - 1; j++) {
      double mj = -l + j;
      double c = sqrt((double)l * (l + 1) - mj * (mj + 1));
      A[(size_t)j * n + j + 1] = -c / 2.0;
      A[(size_t)(j + 1) * n + j] = -c / 2.0;
    }
    w.assign(n, 0.0);
    jacobi_sym(n, A, V, w);
    for (int r = 0; r < n; r++)
      for (int b2 = 0; b2 < n; b2++) U[off2c(l) + r * n + b2] = (float)V[(size_t)r * n + b2];
    for (int b2 = 0; b2 < n; b2++) lam[l * l + b2] = (double)llround(w[b2]); // Jy spectrum is exactly -l..l
  }
  for (int a = 0; a < 6; a++) {
    double al = 2.0 * M_PI * a / 6.0;
    for (int mi = 0; mi < 63; mi++) { int m = mi - 31; PAc[a * 63 + mi] = (float)cos(m * al); PAs[a * 63 + mi] = (float)sin(m * al); }
  }
  for (int c = 0; c < 6; c++) {
    double ga = -2.0 * M_PI + 4.0 * M_PI * c / 5.0;  // linspace(-2pi, 2pi, 6)
    for (int mi = 0; mi < 63; mi++) { int m = mi - 31; PGc[c * 63 + mi] = (float)cos(m * ga); PGs[c * 63 + mi] = (float)sin(m * ga); }
  }
  return ht;
}

// ---------------------------------------------------------------- device helpers
#define DEVFN static __device__ __forceinline__
DEVFN int isqrt_i(int p) {
  int l = (int)sqrtf((float)p);
  while (l * l > p) --l;
  while ((l + 1) * (l + 1) <= p) ++l;
  return l;
}

// ---------------------------------------------------------------- kernels
// trig tables: cos/sin(beta * lambda) for every (beta row, packed l*l+b)
__global__ void k_trig(const double* __restrict__ lam, const double* __restrict__ betas, float2* __restrict__ trig) {
  int id = blockIdx.x * blockDim.x + threadIdx.x;
  if (id >= 227 * 1024) return;
  int row = id >> 10, p = id & 1023;
  double a = betas[row] * lam[p];
  double s, c;
  sincos(a, &s, &c);
  trig[id] = make_float2((float)c, (float)s);
}

// W_s2[k][l*l+mi] = d^l_{m0}(beta_b[k]) * wb[k]
__global__ void k_ws2(const float* __restrict__ U, const float2* __restrict__ Tb, const float* __restrict__ wb, float* __restrict__ W) {
  int id = blockIdx.x * blockDim.x + threadIdx.x;
  if (id >= 128 * 1024) return;
  int k = id >> 10, p = id & 1023;
  int l = isqrt_i(p); int mi = p - l * l; int n = 2 * l + 1;
  const float* Ul = U + off2c(l);
  const float2* T = Tb + (size_t)k * 1024 + l * l;
  float ac = 0, as = 0;
  for (int b = 0; b < n; b++) { float uu = Ul[mi * n + b] * Ul[l * n + b]; ac += uu * T[b].x; as += uu * T[b].y; }
  int q = (mi - l) & 3;
  float v = (q & 1) ? as : ac; if (q & 2) v = -v;
  W[id] = v * wb[k];
}

// generic packed wigner-d build: out[k][off2(l)+r*(2l+1)+c] = d^l_{rc}(beta_k)
__global__ void k_wig(const float* __restrict__ U, const float2* __restrict__ trig, float* __restrict__ out, int S2L) {
  int l = blockIdx.y, k = blockIdx.z;
  int n = 2 * l + 1;
  int t = blockIdx.x * blockDim.x + threadIdx.x;
  if (t >= n * n) return;
  int r = t / n, c = t - r * n;
  const float* Ul = U + off2c(l);
  const float2* T = trig + (size_t)k * 1024 + l * l;
  float ac = 0, as = 0;
  for (int b = 0; b < n; b++) { float uu = Ul[r * n + b] * Ul[c * n + b]; ac += uu * T[b].x; as += uu * T[b].y; }
  int q = (r - c) & 3;
  float v = (q & 1) ? as : ac; if (q & 2) v = -v;
  out[(size_t)k * S2L + off2c(l) + t] = v;
}

// 1x1 conv + relu: h1[z,o,hw]
__global__ void k_conv1(const float* __restrict__ x, const float* __restrict__ w1, const float* __restrict__ b1, float* __restrict__ h1) {
  int id = blockIdx.x * blockDim.x + threadIdx.x;
  if (id >= 2 * 16 * 16384) return;
  int hw = id & 16383; int zo = id >> 14; int o = zo & 15; int z = zo >> 4;
  float acc = b1[o];
  for (int c = 0; c < 4; c++) acc += w1[o * 4 + c] * x[(size_t)(z * 4 + c) * 16384 + hw];
  h1[id] = fmaxf(acc, 0.f);
}

// alpha-DFT (layer2): xf[zi,k,j] = (1/128) sum_a h1[zi,k,a] e^{-2pi i (j-31) a/128}
__global__ void k_dft_a(const float* __restrict__ h1, float2* __restrict__ xf) {
  __shared__ float2 tw[128];
  int tid = threadIdx.x;
  if (tid < 128) { float ang = 6.28318530717958647692f * tid / 128.f; tw[tid] = make_float2(cosf(ang), -sinf(ang)); }
  __syncthreads();
  int id = blockIdx.x * blockDim.x + tid;
  if (id >= 2 * 16 * 128 * 63) return;
  int j = id % 63; int rest = id / 63; int k = rest & 127; int zi = rest >> 7;
  const float* row = h1 + ((size_t)zi * 128 + k) * 128;
  int mm = ((j - 31) + 128) & 127;
  float2 acc = make_float2(0.f, 0.f);
  int t = 0;
  for (int a = 0; a < 128; a++) {
    float2 w = tw[t];
    float hv = row[a];
    acc.x += hv * w.x; acc.y += hv * w.y;
    t += mm; t &= 127;
  }
  xf[id] = make_float2(acc.x / 128.f, acc.y / 128.f);
}

// X2[zi][l*l+mi] = sum_k Ws2[k][p] * xf2[zi,k,jm]
__global__ void k_x2(const float* __restrict__ W, const float2* __restrict__ xf, float2* __restrict__ X) {
  int id = blockIdx.x * blockDim.x + threadIdx.x;
  if (id >= 2 * 16 * 1024) return;
  int p = id & 1023; int zi = id >> 10;
  int l = isqrt_i(p); int mi = p - l * l; int jm = mi - l + 31;
  float2 acc = make_float2(0.f, 0.f);
  for (int k = 0; k < 128; k++) {
    float w = W[(size_t)k * 1024 + p];
    float2 v = xf[((size_t)zi * 128 + k) * 63 + jm];
    acc.x += w * v.x; acc.y += w * v.y;
  }
  X[id] = acc;
}

// kappa2[i*16+o][j] = sum_a k2[i,o,a] e^{i (j-31) alpha_a}
__global__ void k_kap2(const float* __restrict__ k2, const float* __restrict__ PAc, const float* __restrict__ PAs, float2* __restrict__ kap) {
  int id = blockIdx.x * blockDim.x + threadIdx.x;
  if (id >= 16 * 16 * 63) return;
  int j = id % 63; int io = id / 63;
  float2 acc = make_float2(0.f, 0.f);
  for (int a = 0; a < 6; a++) {
    float kv = k2[io * 6 + a];
    acc.x += kv * PAc[a * 63 + j]; acc.y += kv * PAs[a * 63 + j];
  }
  kap[id] = acc;
}

// Y2[z,o,pk] = sum_i X2[z,i,l*l+mi] * conj(d^l_{n0} kappa2[i,o,jn])
__global__ void k_y2(const float2* __restrict__ X, const float2* __restrict__ kap, const float* __restrict__ d3, float2* __restrict__ Y) {
  int l = blockIdx.y; int n21 = 2 * l + 1;
  int t = blockIdx.x * blockDim.x + threadIdx.x;
  if (t >= n21 * n21) return;
  int zo = blockIdx.z; int o = zo & 15; int z = zo >> 4;
  int mi = t / n21, ni = t - mi * n21;
  float dv = d3[off2c(l) + ni * n21 + l];
  int jn = ni - l + 31;
  float2 acc = make_float2(0.f, 0.f);
  for (int i = 0; i < 16; i++) {
    float2 xv = X[(size_t)(z * 16 + i) * 1024 + l * l + mi];
    float2 kv = kap[(size_t)(i * 16 + o) * 63 + jn];
    acc.x += dv * (xv.x * kv.x + xv.y * kv.y);
    acc.y += dv * (xv.y * kv.x - xv.x * kv.y);
  }
  Y[(size_t)(z * 16 + o) * S2_32 + off2c(l) + t] = acc;
}

// ---------------------------------------------------------------- k_y as fused complex GEMM (v1 — verified, 0 bank conflicts)
// Y[z,o,l,mi,ni] = sum_{i,p} X[z,i,l,mi,p] * (d^l[ni,p] * conj(kap[i,o,jn,jp]))
// GEMM per (z,l): M=n21 (mi), N=CO*n21 (o,ni), K=CI*n21 (i,p); B built on the fly.
template <int CI, int CO, int L>
__global__ __launch_bounds__(256) void k_y_gemm(const float2* __restrict__ X, const float2* __restrict__ kap,
                                                const float* __restrict__ dtab, float2* __restrict__ Y, int S2L) {
  constexpr int NF = 2 * L - 1;
  constexpr int BM = 32, BN = 64, BK = 32;
  const int l = blockIdx.y;
  const int n21 = 2 * l + 1;
  const int Kdim = CI * n21;
  const int N = CO * n21;
  const int ntn = (N + BN - 1) / BN;
  const int ntm = (n21 + BM - 1) / BM;
  if ((int)blockIdx.x >= ntm * ntn) return;
  const int tm = blockIdx.x / ntn, tn = blockIdx.x % ntn;
  const int z = blockIdx.z;
  const int off = off2c(l);
  const float2* Xz = X + (size_t)z * CI * S2L + off;
  float2* Yz = Y + (size_t)z * CO * S2L + off;
  const float* dl = dtab + off;

  __shared__ float2 As[BM][BK + 1];
  __shared__ float2 Bs[BK][BN + 1];
  __shared__ int nLUT_o[BN];
  __shared__ short nLUT_ni[BN];

  const int tid = threadIdx.x;
  if (tid < BN) {
    int ng = tn * BN + tid;
    int o = ng / n21;
    nLUT_o[tid] = (ng < N) ? o : -1;
    nLUT_ni[tid] = (short)(ng - o * n21);
  }
  const int kk = tid & 31;   // load lane: K index within tile (fixed per thread)
  const int rr = tid >> 5;   // 0..7
  const int mrow = tid >> 4; // 0..15 compute row base
  const int ncol = tid & 15; // compute col base
  float2 acc[2][4];
  #pragma unroll
  for (int a = 0; a < 2; a++)
    #pragma unroll
    for (int b = 0; b < 4; b++) acc[a][b] = make_float2(0.f, 0.f);
  __syncthreads();

  for (int k0 = 0; k0 < Kdim; k0 += BK) {
    int kg = k0 + kk;
    int i = (unsigned)kg / (unsigned)n21;
    int p = kg - i * n21;
    bool kok = kg < Kdim;
    // A fill: As[m][kk] = X[z,i,mi,p]
    #pragma unroll
    for (int s = 0; s < 4; s++) {
      int m = rr + s * 8;
      int mg = tm * BM + m;
      float2 v = make_float2(0.f, 0.f);
      if (kok && mg < n21) v = Xz[(size_t)i * S2L + mg * n21 + p];
      As[m][kk] = v;
    }
    // B fill: Bs[kk][nn] = d[ni,p] * conj(kap[i,o,jn,jp])
    int jp = p - l + (L - 1);
    #pragma unroll
    for (int s = 0; s < 8; s++) {
      int nn = rr + s * 8;
      float2 v = make_float2(0.f, 0.f);
      int o = nLUT_o[nn];
      if (kok && o >= 0) {
        int ni = nLUT_ni[nn];
        float dv = dl[ni * n21 + p];
        int jn = ni - l + (L - 1);
        float2 kv = kap[(size_t)(i * CO + o) * NF * NF + jn * NF + jp];
        v = make_float2(dv * kv.x, -dv * kv.y);
      }
      Bs[kk][nn] = v;
    }
    __syncthreads();
    #pragma unroll
    for (int q = 0; q < BK; q++) {
      float2 a0 = As[mrow][q];
      float2 a1 = As[mrow + 16][q];
      #pragma unroll
      for (int j = 0; j < 4; j++) {
        float2 b = Bs[q][ncol + j * 16];
        acc[0][j].x += a0.x * b.x - a0.y * b.y;
        acc[0][j].y += a0.x * b.y + a0.y * b.x;
        acc[1][j].x += a1.x * b.x - a1.y * b.y;
        acc[1][j].y += a1.x * b.y + a1.y * b.x;
      }
    }
    __syncthreads();
  }
  #pragma unroll
  for (int sm = 0; sm < 2; sm++) {
    int mg = tm * BM + mrow + sm * 16;
    if (mg >= n21) continue;
    #pragma unroll
    for (int j = 0; j < 4; j++) {
      int nn = ncol + j * 16;
      int o = nLUT_o[nn];
      if (o < 0) continue;
      int ni = nLUT_ni[nn];
      Yz[(size_t)o * S2L + mg * n21 + ni] = acc[sm][j];
    }
  }
}

// F[zc,k,jm,jn] = sum_l (2l+1) * wig[k][pk] * Y[zc][pk]  (dense in (jm,jn))
// v3: jn padded to PAD (multiple of 32) so each (half-)wave owns one jm -> wave-uniform
// loop bounds. Out-of-range lanes clamp n into [-l,l] (in-bounds load) and use weight 0.
// Uniform bounds + unroll-4 -> 8 independent loads in flight (was latency-serialized).
__global__ void k_f(const float* __restrict__ wig, const float2* __restrict__ Y, float2* __restrict__ F,
                    int nzc, int NK, int L, int S2L) {
  int NF = 2 * L - 1;
  int PAD = (NF + 31) & ~31;
  size_t id = (size_t)blockIdx.x * blockDim.x + threadIdx.x;
  size_t tot = (size_t)nzc * NK * NF * PAD;
  if (id >= tot) return;
  int jn = (int)(id % PAD); size_t r1 = id / PAD;
  int jm = (int)(r1 % NF); size_t r2 = r1 / NF;
  int k = (int)(r2 % NK); int zc = (int)(r2 / NK);
  if (jn >= NF) return;
  int m = jm - (L - 1), n = jn - (L - 1);
  int am = m < 0 ? -m : m, an = n < 0 ? -n : n;
  int lmin = am > an ? am : an;
  float2 acc = make_float2(0.f, 0.f);
  const float* wk = wig + (size_t)k * S2L;
  const float2* Yc = Y + (size_t)zc * S2L;
  #pragma unroll 4
  for (int l = am; l < L; l++) {
    int n21 = 2 * l + 1;
    int nc = n < -l ? -l : (n > l ? l : n);
    int pk = off2c(l) + (m + l) * n21 + (nc + l);
    float g = (l >= lmin) ? (float)n21 : 0.f;
    float w = wk[pk] * g;
    float2 yv = Yc[pk];
    acc.x += w * yv.x; acc.y += w * yv.y;
  }
  F[(((size_t)zc * NK + k) * NF + jm) * NF + jn] = acc;
}

// fused 2-stage inverse DFT  F[zc,k,:,:] -> h[zc,k,u,v] (+bias, relu)
template <int L, int B2>
__global__ void k_synth(const float2* __restrict__ F, const float* __restrict__ bias, float* __restrict__ h, int C, int NK) {
  constexpr int NF = 2 * L - 1;
  __shared__ float2 Ft[NF * NF];
  __shared__ float2 Gt[NF * B2];
  __shared__ float2 tw[B2];
  int bid = blockIdx.x;         // zc*NK + k
  int zc = bid / NK;
  int c = zc % C;
  int tid = threadIdx.x, nt = blockDim.x;
  for (int t = tid; t < B2; t += nt) { float ang = 6.28318530717958647692f * t / B2; tw[t] = make_float2(cosf(ang), sinf(ang)); }
  const float2* Fb = F + (size_t)bid * NF * NF;
  for (int idx = tid; idx < NF * NF; idx += nt) Ft[idx] = Fb[idx];
  __syncthreads();
  for (int idx = tid; idx < NF * B2; idx += nt) {
    int jm = idx / B2, v = idx - jm * B2;
    float2 acc = make_float2(0.f, 0.f);
    int t = ((-(L - 1) * v) % B2 + B2) % B2;
    for (int jn = 0; jn < NF; jn++) {
      float2 fv = Ft[jm * NF + jn];
      float2 w = tw[t];
      acc.x += fv.x * w.x - fv.y * w.y;
      acc.y += fv.x * w.y + fv.y * w.x;
      t += v; if (t >= B2) t -= B2;
    }
    Gt[idx] = acc;
  }
  __syncthreads();
  float bv = bias[c];
  float* hb = h + (size_t)bid * B2 * B2;
  for (int idx = tid; idx < B2 * B2; idx += nt) {
    int u = idx / B2, v = idx - u * B2;
    float acc = 0;
    int t = ((-(L - 1) * u) % B2 + B2) % B2;
    for (int jm = 0; jm < NF; jm++) {
      float2 gv = Gt[jm * B2 + v];
      float2 w = tw[t];
      acc += gv.x * w.x - gv.y * w.y;
      t += u; if (t >= B2) t -= B2;
    }
    hb[idx] = fmaxf(acc + bv, 0.f);
  }
}

// fused 2-stage forward DFT: h[zc,k,:,:] -> xf[zc,k,jm,jn] (truncated, /B2^2)
template <int L, int B2>
__global__ void k_fwd(const float* __restrict__ h, float2* __restrict__ xf) {
  constexpr int NF = 2 * L - 1;
  __shared__ float ht[B2 * B2];
  __shared__ float2 Tt[B2 * NF];
  __shared__ float2 tw[B2];
  int bid = blockIdx.x;
  int tid = threadIdx.x, nt = blockDim.x;
  for (int t = tid; t < B2; t += nt) { float ang = 6.28318530717958647692f * t / B2; tw[t] = make_float2(cosf(ang), -sinf(ang)); }
  const float* hb = h + (size_t)bid * B2 * B2;
  for (int idx = tid; idx < B2 * B2; idx += nt) ht[idx] = hb[idx];
  __syncthreads();
  for (int idx = tid; idx < B2 * NF; idx += nt) {
    int u = idx / NF, jn = idx - u * NF;
    int mm = ((jn - (L - 1)) % B2 + B2) % B2;
    float2 acc = make_float2(0.f, 0.f);
    int t = 0;
    for (int v = 0; v < B2; v++) {
      float hv = ht[u * B2 + v];
      float2 w = tw[t];
      acc.x += hv * w.x; acc.y += hv * w.y;
      t += mm; if (t >= B2) t -= B2;
    }
    Tt[idx] = acc;
  }
  __syncthreads();
  float2* xb = xf + (size_t)bid * NF * NF;
  const float inv = 1.f / ((float)B2 * (float)B2);
  for (int idx = tid; idx < NF * NF; idx += nt) {
    int jm = idx / NF, jn = idx - jm * NF;
    int mm = ((jm - (L - 1)) % B2 + B2) % B2;
    float2 acc = make_float2(0.f, 0.f);
    int t = 0;
    for (int u = 0; u < B2; u++) {
      float2 tv = Tt[u * NF + jn];
      float2 w = tw[t];
      acc.x += tv.x * w.x - tv.y * w.y;
      acc.y += tv.x * w.y + tv.y * w.x;
      t += mm; if (t >= B2) t -= B2;
    }
    xb[idx] = make_float2(acc.x * inv, acc.y * inv);
  }
}

// X[zi][pk] = sum_k wgt[k] * wig[k][pk] * xf[zi,k,jm,jn]
__global__ void k_xc(const float* __restrict__ wig, const float* __restrict__ wgt, const float2* __restrict__ xf,
                     float2* __restrict__ X, int NK, int L, int S2L) {
  int NF = 2 * L - 1;
  int l = blockIdx.y; int n21 = 2 * l + 1;
  int t = blockIdx.x * blockDim.x + threadIdx.x;
  if (t >= n21 * n21) return;
  int zi = blockIdx.z;
  int mi = t / n21, ni = t - mi * n21;
  int jm = mi - l + (L - 1), jn = ni - l + (L - 1);
  int pk = off2c(l) + t;
  float2 acc = make_float2(0.f, 0.f);
  for (int k = 0; k < NK; k++) {
    float w = wig[(size_t)k * S2L + pk] * wgt[k];
    float2 v = xf[((size_t)zi * NK + k) * NF * NF + jm * NF + jn];
    acc.x += w * v.x; acc.y += w * v.y;
  }
  X[(size_t)zi * S2L + pk] = acc;
}

// kappa[io][jn][jp] = sum_{a,c} ker[io,a*6+c] e^{i m_n alpha_a} e^{i m_p gamma_c}
__global__ void k_kap(const float* __restrict__ ker, const float* __restrict__ PAc, const float* __restrict__ PAs,
                      const float* __restrict__ PGc, const float* __restrict__ PGs,
                      float2* __restrict__ kap, int NIO, int NF, int poff) {
  int id = blockIdx.x * blockDim.x + threadIdx.x;
  if (id >= NIO * NF * NF) return;
  int jp = id % NF; int r = id / NF; int jn = r % NF; int io = r / NF;
  float2 acc = make_float2(0.f, 0.f);
  for (int a = 0; a < 6; a++) {
    float pac = PAc[a * 63 + jn + poff], pas = PAs[a * 63 + jn + poff];
    for (int c = 0; c < 6; c++) {
      float kv = ker[io * 36 + a * 6 + c];
      float pgc = PGc[c * 63 + jp + poff], pgs = PGs[c * 63 + jp + poff];
      acc.x += kv * (pac * pgc - pas * pgs);
      acc.y += kv * (pac * pgs + pas * pgc);
    }
  }
  kap[id] = acc;
}

// feat[zc] = sum_{beta,u,v} h5[zc,beta,u,v] * wint[beta]
__global__ void k_feat(const float* __restrict__ h5, const float* __restrict__ wint, float* __restrict__ feat) {
  __shared__ float red[256];
  int zc = blockIdx.x;
  const float* hb = h5 + (size_t)zc * 32768;
  float acc = 0;
  for (int idx = threadIdx.x; idx < 32768; idx += 256) acc += hb[idx] * wint[idx >> 10];
  red[threadIdx.x] = acc;
  __syncthreads();
  for (int s = 128; s > 0; s >>= 1) { if (threadIdx.x < s) red[threadIdx.x] += red[threadIdx.x + s]; __syncthreads(); }
  if (threadIdx.x == 0) feat[zc] = red[0];
}

// MLP head per batch row
__global__ void k_head(const float* __restrict__ feat, const float* __restrict__ m, const float* __restrict__ wm,
                       const float* __restrict__ bm, const float* __restrict__ wl1, const float* __restrict__ bl1,
                       const float* __restrict__ wl2, const float* __restrict__ bl2, float* __restrict__ out) {
  __shared__ float zin[68];
  __shared__ float red[512];
  int z = blockIdx.x, tid = threadIdx.x;
  if (tid < 64) zin[tid] = feat[z * 64 + tid];
  else if (tid < 68) zin[tid] = fmaxf(m[z] * wm[tid - 64] + bm[tid - 64], 0.f);
  __syncthreads();
  float part = 0;
  for (int q = tid; q < 500; q += 512) {
    float acc = bl1[q];
    for (int j = 0; j < 68; j++) acc += zin[j] * wl1[q * 68 + j];
    part += fmaxf(acc, 0.f) * wl2[q];
  }
  red[tid] = part;
  __syncthreads();
  for (int s = 256; s > 0; s >>= 1) { if (tid < s) red[tid] += red[tid + s]; __syncthreads(); }
  if (tid == 0) out[z] = red[0] + bl2[0];
}

// ---------------------------------------------------------------- launch
extern "C" void kernel_launch(void* const* d_in, const int* in_sizes, int n_in,
                              void* d_out, int out_size, void* d_ws, size_t ws_size,
                              hipStream_t stream) {
  static HostTables HT = build_tables();  // host-only, once

  if (ws_size < WS_REQ) {
    fprintf(stderr, "[s2cnn] ws too small: need %zu bytes, got %zu\n", (size_t)WS_REQ, ws_size);
    return;
  }
  if (n_in < 18) { fprintf(stderr, "[s2cnn] bad n_in %d\n", n_in); return; }

  const float* x   = (const float*)d_in[0];
  const float* mI  = (const float*)d_in[1];
  const float* w1  = (const float*)d_in[2];
  const float* b1  = (const float*)d_in[3];
  const float* k2  = (const float*)d_in[4];
  const float* bb2 = (const float*)d_in[5];
  const float* k3  = (const float*)d_in[6];
  const float* bb3 = (const float*)d_in[7];
  const float* k4  = (const float*)d_in[8];
  const float* bb4 = (const float*)d_in[9];
  const float* k5  = (const float*)d_in[10];
  const float* bb5 = (const float*)d_in[11];
  const float* wm  = (const float*)d_in[12];
  const float* bm  = (const float*)d_in[13];
  const float* wl1 = (const float*)d_in[14];
  const float* bl1 = (const float*)d_in[15];
  const float* wl2 = (const float*)d_in[16];
  const float* bl2 = (const float*)d_in[17];
  float* out = (float*)d_out;

  char* ws = (char*)d_ws;
  // upload constant blob (192 KB)
  hipMemcpyAsync(ws, HT.blob.data(), BLOB_BYTES, hipMemcpyHostToDevice, stream);

  const double* dLam  = (const double*)(ws + B_LAM);
  const double* dBet  = (const double*)(ws + B_BETAS);
  const float*  dU    = (const float*)(ws + B_U);
  const float*  dPAc  = (const float*)(ws + B_PAC);
  const float*  dPAs  = (const float*)(ws + B_PAS);
  const float*  dPGc  = (const float*)(ws + B_PGC);
  const float*  dPGs  = (const float*)(ws + B_PGS);
  const float*  dWb   = (const float*)(ws + B_WB);
  const float*  dWh   = (const float*)(ws + B_WH);
  const float*  dWq   = (const float*)(ws + B_WQ);
  const float*  dWint = (const float*)(ws + B_WINT);

  float2* TRIG = (float2*)(ws + O_TRIG);
  float2* Tb = TRIG;                 // 128 rows
  float2* Th = TRIG + (size_t)128 * 1024;
  float2* Tq = TRIG + (size_t)192 * 1024;
  float2* Ts16 = TRIG + (size_t)224 * 1024;
  float2* Ts8  = TRIG + (size_t)225 * 1024;
  float2* Ts4  = TRIG + (size_t)226 * 1024;
  float* WS2   = (float*)(ws + O_WS2);
  float* WIGH  = (float*)(ws + O_WIGH);
  float* WIG16 = (float*)(ws + O_WIG16);
  float* WIGQ  = (float*)(ws + O_WIGQ);
  float* D3    = (float*)(ws + O_D3);
  float* D4    = (float*)(ws + O_D4);
  float* D5    = (float*)(ws + O_D5);
  float* FEAT  = (float*)(ws + O_FEAT);
  char* A0 = ws + O_A0;
  char* A1 = ws + O_A1;
  char* A2 = ws + O_A2;
  char* A3 = ws + O_A3;
  char* A4 = ws + O_A4;

  // ---- build tables on device (cheap, every call: ws is re-poisoned)
  k_trig<<<(227 * 1024 + 255) / 256, 256, 0, stream>>>(dLam, dBet, TRIG);
  k_ws2<<<(128 * 1024 + 255) / 256, 256, 0, stream>>>(dU, Tb, dWb, WS2);
  k_wig<<<dim3(16, 32, 64), 256, 0, stream>>>(dU, Th, WIGH, S2_32);
  k_wig<<<dim3(4, 16, 64), 256, 0, stream>>>(dU, Th, WIG16, S2_16);
  k_wig<<<dim3(4, 16, 32), 256, 0, stream>>>(dU, Tq, WIGQ, S2_16);
  k_wig<<<dim3(16, 32, 1), 256, 0, stream>>>(dU, Ts16, D3, S2_32);
  k_wig<<<dim3(4, 16, 1), 256, 0, stream>>>(dU, Ts8, D4, S2_16);
  k_wig<<<dim3(4, 16, 1), 256, 0, stream>>>(dU, Ts4, D5, S2_16);

  // ---- layer 1: 1x1 conv + relu -> h1 (A2)
  float* h1 = (float*)A2;
  k_conv1<<<(2 * 16 * 16384 + 255) / 256, 256, 0, stream>>>(x, w1, b1, h1);

  // ---- layer 2: s2 conv
  float2* xf2 = (float2*)A0;
  k_dft_a<<<(2 * 16 * 128 * 63 + 255) / 256, 256, 0, stream>>>(h1, xf2);
  float2* X2 = (float2*)A3;
  k_x2<<<(2 * 16 * 1024 + 255) / 256, 256, 0, stream>>>(WS2, xf2, X2);
  float2* kap2 = (float2*)A4;
  k_kap2<<<(16 * 16 * 63 + 255) / 256, 256, 0, stream>>>(k2, dPAc, dPAs, kap2);
  float2* Y2 = (float2*)A1;
  k_y2<<<dim3(16, 32, 32), 256, 0, stream>>>(X2, kap2, D3, Y2);
  float2* F2 = (float2*)A0;
  k_f<<<(2 * 16 * 64 * 63 * 64 + 255) / 256, 256, 0, stream>>>(WIGH, Y2, F2, 32, 64, 32, S2_32);
  float* h2 = (float*)A1;
  k_synth<32, 64><<<2 * 16 * 64, 256, 0, stream>>>(F2, bb2, h2, 16, 64);

  // ---- layer 3: so3 conv (b=32, L=32)
  float2* xf3 = (float2*)A0;
  k_fwd<32, 64><<<2 * 16 * 64, 256, 0, stream>>>(h2, xf3);
  float2* X3 = (float2*)A2;
  k_xc<<<dim3(16, 32, 2 * 16), 256, 0, stream>>>(WIGH, dWh, xf3, X3, 64, 32, S2_32);
  float2* kap3 = (float2*)A3;
  k_kap<<<(16 * 32 * 63 * 63 + 255) / 256, 256, 0, stream>>>(k3, dPAc, dPAs, dPGc, dPGs, kap3, 16 * 32, 63, 0);
  float2* Y3 = (float2*)A4;
  k_y_gemm<16, 32, 32><<<dim3(64, 32, 2), 256, 0, stream>>>(X3, kap3, D3, Y3, S2_32);
  float* h3 = (float*)A1;
  for (int z = 0; z < 2; z++) {
    float2* F3 = (float2*)A0;
    k_f<<<(32 * 64 * 63 * 64 + 255) / 256, 256, 0, stream>>>(WIGH, Y3 + (size_t)z * 32 * S2_32, F3, 32, 64, 32, S2_32);
    k_synth<32, 64><<<32 * 64, 256, 0, stream>>>(F3, bb3, h3 + (size_t)z * 32 * 64 * 4096, 32, 64);
  }

  // ---- layer 4: so3 conv (b=32 -> 16, L=16)
  float2* xf4 = (float2*)A0;
  k_fwd<16, 64><<<2 * 32 * 64, 256, 0, stream>>>(h3, xf4);
  float2* X4 = (float2*)A2;
  k_xc<<<dim3(4, 16, 2 * 32), 256, 0, stream>>>(WIG16, dWh, xf4, X4, 64, 16, S2_16);
  float2* kap4 = (float2*)A3;
  k_kap<<<(32 * 32 * 31 * 31 + 255) / 256, 256, 0, stream>>>(k4, dPAc, dPAs, dPGc, dPGs, kap4, 32 * 32, 31, 16);
  float2* Y4 = (float2*)A4;
  k_y_gemm<32, 32, 16><<<dim3(16, 16, 2), 256, 0, stream>>>(X4, kap4, D4, Y4, S2_16);
  float2* F4 = (float2*)A1;
  k_f<<<(2 * 32 * 32 * 31 * 32 + 255) / 256, 256, 0, stream>>>(WIGQ, Y4, F4, 64, 32, 16, S2_16);
  float* h4 = (float*)A0;
  k_synth<16, 32><<<2 * 32 * 32, 256, 0, stream>>>(F4, bb4, h4, 32, 32);

  // ---- layer 5: so3 conv (b=16, L=16)
  float2* xf5 = (float2*)A1;
  k_fwd<16, 32><<<2 * 32 * 32, 256, 0, stream>>>(h4, xf5);
  float2* X5 = (float2*)A2;
  k_xc<<<dim3(4, 16, 2 * 32), 256, 0, stream>>>(WIGQ, dWq, xf5, X5, 32, 16, S2_16);
  float2* kap5 = (float2*)A3;
  k_kap<<<(32 * 64 * 31 * 31 + 255) / 256, 256, 0, stream>>>(k5, dPAc, dPAs, dPGc, dPGs, kap5, 32 * 64, 31, 16);
  float2* Y5 = (float2*)A4;
  k_y_gemm<32, 64, 16><<<dim3(31, 16, 2), 256, 0, stream>>>(X5, kap5, D5, Y5, S2_16);
  float2* F5 = (float2*)A0;
  k_f<<<(2 * 64 * 32 * 31 * 32 + 255) / 256, 256, 0, stream>>>(WIGQ, Y5, F5, 128, 32, 16, S2_16);
  float* h5 = (float*)A1;
  k_synth<16, 32><<<2 * 64 * 32, 256, 0, stream>>>(F5, bb5, h5, 64, 32);

  // ---- head
  k_feat<<<128, 256, 0, stream>>>(h5, dWint, FEAT);
  k_head<<<2, 512, 0, stream>>>(FEAT, mI, wm, bm, wl1, bl1, wl2, bl2, out);
}